// Round 1
// baseline (332.133 us; speedup 1.0000x reference)
//
#include <hip/hip_runtime.h>

typedef unsigned short u16;
typedef unsigned int u32;
typedef float f32x4 __attribute__((ext_vector_type(4)));
typedef __bf16 bf16x8 __attribute__((ext_vector_type(8)));

#define SEQ 2048
#define DM 1024

__device__ __forceinline__ float bf2f(u16 a){
  u32 b = ((u32)a) << 16; float f; __builtin_memcpy(&f, &b, 4); return f;
}
__device__ __forceinline__ u16 f2bf(float f){
  u32 b; __builtin_memcpy(&b, &f, 4);
  b += 0x7fffu + ((b >> 16) & 1u);
  return (u16)(b >> 16);
}

__device__ __forceinline__ void gload16(const void* g, void* l){
  __builtin_amdgcn_global_load_lds((const __attribute__((address_space(1))) u32*)g,
                                   (__attribute__((address_space(3))) u32*)l, 16, 0, 0);
}

// ---------------- weight convert + transpose: W[K][N] f32 -> WT[N][K] bf16 ----------------
__global__ __launch_bounds__(256) void ktranspose(const float* __restrict__ W, u16* __restrict__ WT,
                                                  int K, int N){
  __shared__ float tile[64][65];
  int kb = blockIdx.y << 6, nb = blockIdx.x << 6;
  int t = threadIdx.x;
  #pragma unroll
  for (int i = 0; i < 4; i++){
    int idx = t + (i << 8);
    int r = idx >> 4, c = (idx & 15) << 2;
    float4 v = *(const float4*)(W + (size_t)(kb + r) * N + nb + c);
    tile[r][c] = v.x; tile[r][c+1] = v.y; tile[r][c+2] = v.z; tile[r][c+3] = v.w;
  }
  __syncthreads();
  #pragma unroll
  for (int i = 0; i < 2; i++){
    int idx = t + (i << 8);
    int n = idx >> 3, k8 = (idx & 7) << 3;
    union { u16 s[8]; int4 v; } u;
    #pragma unroll
    for (int j = 0; j < 8; j++) u.s[j] = f2bf(tile[k8 + j][n]);
    *(int4*)(WT + (size_t)(nb + n) * K + kb + k8) = u.v;
  }
}

// ---------------- layernorm: x f32 -> h bf16 ----------------
__global__ __launch_bounds__(256) void kln(const float* __restrict__ x, const float* __restrict__ gg,
                                           const float* __restrict__ bb, u16* __restrict__ h){
  int row = blockIdx.x, t = threadIdx.x;
  float4 xv = ((const float4*)(x + (size_t)row * DM))[t];
  float s  = xv.x + xv.y + xv.z + xv.w;
  float s2 = xv.x*xv.x + xv.y*xv.y + xv.z*xv.z + xv.w*xv.w;
  #pragma unroll
  for (int o = 1; o < 64; o <<= 1){ s += __shfl_xor(s, o); s2 += __shfl_xor(s2, o); }
  __shared__ float r1[4], r2[4];
  if ((t & 63) == 0){ r1[t >> 6] = s; r2[t >> 6] = s2; }
  __syncthreads();
  float S = r1[0]+r1[1]+r1[2]+r1[3], S2 = r2[0]+r2[1]+r2[2]+r2[3];
  float mu = S * (1.0f/DM);
  float var = S2 * (1.0f/DM) - mu*mu;
  float rstd = rsqrtf(var + 1e-5f);
  float4 gv = ((const float4*)gg)[t], bv = ((const float4*)bb)[t];
  ushort4 o;
  o.x = f2bf((xv.x - mu)*rstd*gv.x + bv.x);
  o.y = f2bf((xv.y - mu)*rstd*gv.y + bv.y);
  o.z = f2bf((xv.z - mu)*rstd*gv.z + bv.z);
  o.w = f2bf((xv.w - mu)*rstd*gv.w + bv.w);
  ((ushort4*)(h + (size_t)row * DM))[t] = o;
}

// ---------------- GEMM core: 128x128 tile, BK=64, 4 waves, XOR-swizzled LDS ----------------
// A: [M][K] bf16 row-major (optionally 3 chunks of K=1024 each), B: [N][K] bf16 row-major.
template<int NCHUNK>
__device__ __forceinline__ void gemm_core(const u16* A0, const u16* A1, const u16* A2, int lda,
                                          const u16* B, int ldb, int K, int m0, int n0,
                                          u16* ldsA, u16* ldsB, f32x4 (&acc)[4][4])
{
  const int t = threadIdx.x, lane = t & 63, w = t >> 6;
  const int wm = w >> 1, wn = w & 1;
  int srow[4], scol[4];
  #pragma unroll
  for (int j = 0; j < 4; j++){
    int r = ((w << 2) + j) * 8 + (lane >> 3);
    int csw = (lane & 7) << 4;
    srow[j] = r;
    scol[j] = csw ^ ((r & 7) << 4);   // pre-swizzled source byte offset (involution)
  }
  for (int k0 = 0; k0 < K; k0 += 64){
    const u16* Ab;
    if (NCHUNK == 3){
      int ci = k0 >> 10;
      const u16* cp = (ci == 0) ? A0 : ((ci == 1) ? A1 : A2);
      Ab = cp + (k0 & 1023);
    } else {
      Ab = A0 + k0;
    }
    const u16* Bb = B + k0;
    #pragma unroll
    for (int j = 0; j < 4; j++){
      gload16((const char*)(Ab + (size_t)(m0 + srow[j]) * lda) + scol[j],
              (char*)ldsA + (((w << 2) + j) << 10));
      gload16((const char*)(Bb + (size_t)(n0 + srow[j]) * ldb) + scol[j],
              (char*)ldsB + (((w << 2) + j) << 10));
    }
    __syncthreads();
    #pragma unroll
    for (int kk = 0; kk < 2; kk++){
      bf16x8 a[4], b[4];
      #pragma unroll
      for (int m = 0; m < 4; m++){
        int ra = wm*64 + m*16 + (lane & 15);
        int byt = ra*128 + (((kk << 6) + ((lane >> 4) << 4)) ^ ((ra & 7) << 4));
        a[m] = *(const bf16x8*)((const char*)ldsA + byt);
      }
      #pragma unroll
      for (int n = 0; n < 4; n++){
        int rb = wn*64 + n*16 + (lane & 15);
        int byt = rb*128 + (((kk << 6) + ((lane >> 4) << 4)) ^ ((rb & 7) << 4));
        b[n] = *(const bf16x8*)((const char*)ldsB + byt);
      }
      #pragma unroll
      for (int m = 0; m < 4; m++)
        #pragma unroll
        for (int n = 0; n < 4; n++)
          acc[m][n] = __builtin_amdgcn_mfma_f32_16x16x32_bf16(a[m], b[n], acc[m][n], 0, 0, 0);
    }
    __syncthreads();
  }
}

#define EPI_COORDS \
  const int lane = threadIdx.x & 63, w = threadIdx.x >> 6; \
  const int wm = w >> 1, wn = w & 1;

#define ZERO_ACC f32x4 acc[4][4]; \
  _Pragma("unroll") for (int m = 0; m < 4; m++) _Pragma("unroll") for (int n = 0; n < 4; n++) acc[m][n] = (f32x4){0.f,0.f,0.f,0.f};

__device__ __forceinline__ float phi_elu(float v){ return v > 0.f ? v + 1.f : __expf(v); }

// ---------------- fused QKV projections ----------------
__global__ __launch_bounds__(256) void kqkv(
  const u16* __restrict__ h,
  const u16* wt0, const u16* wt1, const u16* wt2, const u16* wt3, const u16* wt4, const u16* wt5,
  const float* b0, const float* b1, const float* b2, const float* b3, const float* b4, const float* b5,
  u16* phiQ, u16* phiKT, u16* vT, u16* qloc, u16* kloc, u16* vloc)
{
  __shared__ u16 ldsA[8192], ldsB[8192];
  int m0 = blockIdx.x << 7;
  int by = blockIdx.y;
  int wi = by >> 3, n0 = (by & 7) << 7;
  const u16* wsel = wi==0?wt0: wi==1?wt1: wi==2?wt2: wi==3?wt3: wi==4?wt4: wt5;
  const float* bsel = wi==0?b0: wi==1?b1: wi==2?b2: wi==3?b3: wi==4?b4: b5;
  ZERO_ACC
  gemm_core<1>(h, 0, 0, DM, wsel, DM, DM, m0, n0, ldsA, ldsB, acc);
  EPI_COORDS
  #pragma unroll
  for (int n = 0; n < 4; n++){
    int col = n0 + wn*64 + n*16 + (lane & 15);
    float bv = bsel[col];
    #pragma unroll
    for (int m = 0; m < 4; m++){
      int r0 = m0 + wm*64 + m*16 + ((lane >> 4) << 2);
      float e[4];
      #pragma unroll
      for (int r = 0; r < 4; r++) e[r] = acc[m][n][r] + bv;
      if (wi == 0){
        #pragma unroll
        for (int r = 0; r < 4; r++) phiQ[(size_t)(r0 + r) * DM + col] = f2bf(phi_elu(e[r]));
      } else if (wi == 1 || wi == 2){
        union { u16 s[4]; ushort4 v; } o;
        #pragma unroll
        for (int r = 0; r < 4; r++) o.s[r] = f2bf(wi == 1 ? phi_elu(e[r]) : e[r]);
        int bb = r0 >> 11, sl = r0 & 2047;
        u16* dst = (wi == 1) ? phiKT : vT;
        *(ushort4*)(dst + ((size_t)(bb << 10) + col) * SEQ + sl) = o.v;
      } else {
        u16* dst = wi==3 ? qloc : wi==4 ? kloc : vloc;
        #pragma unroll
        for (int r = 0; r < 4; r++) dst[(size_t)(r0 + r) * DM + col] = f2bf(e[r]);
      }
    }
  }
}

// ---------------- kv^T = v^T . phiK^T  (per batch) ----------------
__global__ __launch_bounds__(256) void kkv(const u16* __restrict__ vT, const u16* __restrict__ phiKT,
                                           u16* __restrict__ kvT){
  __shared__ u16 ldsA[8192], ldsB[8192];
  int b = blockIdx.z;
  int m0 = blockIdx.x << 7, n0 = blockIdx.y << 7;
  const u16* A = vT + (size_t)b * DM * SEQ;
  const u16* B = phiKT + (size_t)b * DM * SEQ;
  ZERO_ACC
  gemm_core<1>(A, 0, 0, SEQ, B, SEQ, SEQ, m0, n0, ldsA, ldsB, acc);
  EPI_COORDS
  u16* C = kvT + (size_t)b * DM * DM;
  #pragma unroll
  for (int n = 0; n < 4; n++){
    int col = n0 + wn*64 + n*16 + (lane & 15);
    #pragma unroll
    for (int m = 0; m < 4; m++){
      int r0 = m0 + wm*64 + m*16 + ((lane >> 4) << 2);
      #pragma unroll
      for (int r = 0; r < 4; r++) C[(size_t)(r0 + r) * DM + col] = f2bf(acc[m][n][r]);
    }
  }
}

// ---------------- num = phiQ . kv^T, lin = num / (denom + 1e-6) ----------------
__global__ __launch_bounds__(256) void knum(const u16* __restrict__ phiQ, const u16* __restrict__ kvT,
                                            const float* __restrict__ dn, u16* __restrict__ lin){
  __shared__ u16 ldsA[8192], ldsB[8192];
  int b = blockIdx.z;
  int m0 = blockIdx.x << 7, n0 = blockIdx.y << 7;
  const u16* A = phiQ + (size_t)b * SEQ * DM;
  const u16* B = kvT + (size_t)b * DM * DM;
  ZERO_ACC
  gemm_core<1>(A, 0, 0, DM, B, DM, DM, m0, n0, ldsA, ldsB, acc);
  EPI_COORDS
  #pragma unroll
  for (int n = 0; n < 4; n++){
    int col = n0 + wn*64 + n*16 + (lane & 15);
    #pragma unroll
    for (int m = 0; m < 4; m++){
      int r0 = m0 + wm*64 + m*16 + ((lane >> 4) << 2);
      #pragma unroll
      for (int r = 0; r < 4; r++){
        float d = dn[(b << 11) + r0 + r] + 1e-6f;
        lin[((size_t)(b << 11) + r0 + r) * DM + col] = f2bf(acc[m][n][r] / d);
      }
    }
  }
}

// ---------------- ksum[b][d] = sum_s phiKT[b][d][s] ----------------
__global__ __launch_bounds__(256) void ksumk(const u16* __restrict__ kt, float* __restrict__ ks){
  int row = blockIdx.x, t = threadIdx.x;
  const ushort4* src = (const ushort4*)(kt + (size_t)row * SEQ);
  float s = 0.f;
  for (int i = t; i < 512; i += 256){
    ushort4 v = src[i];
    s += bf2f(v.x) + bf2f(v.y) + bf2f(v.z) + bf2f(v.w);
  }
  #pragma unroll
  for (int o = 1; o < 64; o <<= 1) s += __shfl_xor(s, o);
  __shared__ float red[4];
  if ((t & 63) == 0) red[t >> 6] = s;
  __syncthreads();
  if (t == 0) ks[row] = red[0] + red[1] + red[2] + red[3];
}

// ---------------- denom[row] = phiQ[row] . ksum[b] ----------------
__global__ __launch_bounds__(256) void kdenom(const u16* __restrict__ phiQ, const float* __restrict__ ks,
                                              float* __restrict__ dn){
  int row = blockIdx.x, t = threadIdx.x;
  ushort4 v = ((const ushort4*)(phiQ + (size_t)row * DM))[t];
  float4 kk = ((const float4*)(ks + ((size_t)(row >> 11) << 10)))[t];
  float s = bf2f(v.x)*kk.x + bf2f(v.y)*kk.y + bf2f(v.z)*kk.z + bf2f(v.w)*kk.w;
  #pragma unroll
  for (int o = 1; o < 64; o <<= 1) s += __shfl_xor(s, o);
  __shared__ float red[4];
  if ((t & 63) == 0) red[t >> 6] = s;
  __syncthreads();
  if (t == 0) dn[row] = red[0] + red[1] + red[2] + red[3];
}

// ---------------- sliding-window attention ----------------
__global__ __launch_bounds__(256) void kwin(const u16* __restrict__ qloc, const u16* __restrict__ kloc,
                                            const u16* __restrict__ vloc, const float* __restrict__ rel_bias,
                                            u16* __restrict__ wout)
{
  __shared__ float KV[128 * 68];     // K window, then reused for V
  __shared__ float Ssm[64 * 84];     // scores/probs, per-q range [rlo, rlo+80)
  __shared__ float bias_s[65];
  int qt = blockIdx.x, hh = blockIdx.y, b = blockIdx.z;
  int q0 = qt << 6;
  int t = threadIdx.x;
  int q = t >> 2, sub = t & 3, qq = q & 15;
  size_t base = (size_t)b * SEQ * DM + hh * 64;
  // stage K (fp32, padded stride 68)
  for (int i = t; i < 1024; i += 256){
    int r = i >> 3, seg = i & 7;
    int p = q0 + r - 32;
    float* dst = &KV[r * 68 + (seg << 3)];
    if ((unsigned)p < SEQ){
      int4 raw = *(const int4*)(kloc + base + (size_t)p * DM + (seg << 3));
      const u16* s = (const u16*)&raw;
      #pragma unroll
      for (int j = 0; j < 8; j++) dst[j] = bf2f(s[j]);
    } else {
      #pragma unroll
      for (int j = 0; j < 8; j++) dst[j] = 0.f;
    }
  }
  if (t < 65) bias_s[t] = rel_bias[(t + 32) * 16 + hh];
  float qreg[16];
  {
    const u16* qp = qloc + base + (size_t)(q0 + q) * DM + (sub << 4);
    int4 raw0 = *(const int4*)qp;
    int4 raw1 = *(const int4*)(qp + 8);
    const u16* s0 = (const u16*)&raw0; const u16* s1 = (const u16*)&raw1;
    #pragma unroll
    for (int j = 0; j < 8; j++){ qreg[j] = bf2f(s0[j]); qreg[8 + j] = bf2f(s1[j]); }
  }
  __syncthreads();
  int rlo = (t >> 6) << 4;
  for (int rr = 0; rr < 80; rr++){
    int r = rlo + rr;
    const float* kr = &KV[r * 68 + (sub << 4)];
    float s = 0.f;
    #pragma unroll
    for (int i = 0; i < 16; i++) s += qreg[i] * kr[i];
    s += __shfl_xor(s, 1); s += __shfl_xor(s, 2);
    int wrel = r - q;
    int p = q0 + r - 32;
    float sc = -1e30f;
    if ((unsigned)wrel <= 64u && (unsigned)p < SEQ) sc = s * 0.125f + bias_s[wrel];
    if (sub == 0) Ssm[q * 84 + rr] = sc;
  }
  __syncthreads();
  // stage V into KV
  for (int i = t; i < 1024; i += 256){
    int r = i >> 3, seg = i & 7;
    int p = q0 + r - 32;
    float* dst = &KV[r * 68 + (seg << 3)];
    if ((unsigned)p < SEQ){
      int4 raw = *(const int4*)(vloc + base + (size_t)p * DM + (seg << 3));
      const u16* s = (const u16*)&raw;
      #pragma unroll
      for (int j = 0; j < 8; j++) dst[j] = bf2f(s[j]);
    } else {
      #pragma unroll
      for (int j = 0; j < 8; j++) dst[j] = 0.f;
    }
  }
  // softmax over the 65 in-band entries (split by sub; Ssm untouched by V staging)
  float mloc = -1e30f;
  for (int wrel = sub; wrel <= 64; wrel += 4) mloc = fmaxf(mloc, Ssm[q * 84 + qq + wrel]);
  mloc = fmaxf(mloc, __shfl_xor(mloc, 1));
  mloc = fmaxf(mloc, __shfl_xor(mloc, 2));
  float lloc = 0.f;
  for (int wrel = sub; wrel <= 64; wrel += 4) lloc += __expf(Ssm[q * 84 + qq + wrel] - mloc);
  lloc += __shfl_xor(lloc, 1); lloc += __shfl_xor(lloc, 2);
  float inv = 1.0f / lloc;
  for (int wrel = sub; wrel <= 64; wrel += 4)
    Ssm[q * 84 + qq + wrel] = __expf(Ssm[q * 84 + qq + wrel] - mloc) * inv;
  __syncthreads();
  // PV: V reads are 16-way broadcast across q-groups
  float accv[16];
  #pragma unroll
  for (int i = 0; i < 16; i++) accv[i] = 0.f;
  for (int rr = 0; rr < 80; rr++){
    int r = rlo + rr;
    float pv = Ssm[q * 84 + rr];
    pv = ((unsigned)(r - q) <= 64u) ? pv : 0.f;
    const float* vr = &KV[r * 68 + (sub << 4)];
    #pragma unroll
    for (int i = 0; i < 16; i++) accv[i] += pv * vr[i];
  }
  union { u16 s[16]; int4 v[2]; } ob;
  #pragma unroll
  for (int i = 0; i < 16; i++) ob.s[i] = f2bf(accv[i]);
  u16* dst = wout + base + (size_t)(q0 + q) * DM + (sub << 4);
  *(int4*)dst = ob.v[0];
  *(int4*)(dst + 8) = ob.v[1];
}

// ---------------- gate GEMM 1: relu([lin,win,h] . wg1 + bg1) ----------------
__global__ __launch_bounds__(256) void kgate1(const u16* __restrict__ lin, const u16* __restrict__ win,
                                              const u16* __restrict__ h, const u16* __restrict__ wg1T,
                                              const float* __restrict__ bg1, u16* __restrict__ g1){
  __shared__ u16 ldsA[8192], ldsB[8192];
  int m0 = blockIdx.x << 7, n0 = blockIdx.y << 7;
  ZERO_ACC
  gemm_core<3>(lin, win, h, DM, wg1T, 3072, 3072, m0, n0, ldsA, ldsB, acc);
  EPI_COORDS
  #pragma unroll
  for (int n = 0; n < 4; n++){
    int col = n0 + wn*64 + n*16 + (lane & 15);
    float bv = bg1[col];
    #pragma unroll
    for (int m = 0; m < 4; m++){
      int r0 = m0 + wm*64 + m*16 + ((lane >> 4) << 2);
      #pragma unroll
      for (int r = 0; r < 4; r++){
        float v = acc[m][n][r] + bv;
        g1[(size_t)(r0 + r) * DM + col] = f2bf(v > 0.f ? v : 0.f);
      }
    }
  }
}

// ---------------- gate GEMM 2 + sigmoid + convex combine ----------------
__global__ __launch_bounds__(256) void kgate2(const u16* __restrict__ g1, const u16* __restrict__ wg2T,
                                              const float* __restrict__ bg2, const u16* __restrict__ lin,
                                              const u16* __restrict__ win, u16* __restrict__ outc){
  __shared__ u16 ldsA[8192], ldsB[8192];
  int m0 = blockIdx.x << 7, n0 = blockIdx.y << 7;
  ZERO_ACC
  gemm_core<1>(g1, 0, 0, DM, wg2T, DM, DM, m0, n0, ldsA, ldsB, acc);
  EPI_COORDS
  #pragma unroll
  for (int n = 0; n < 4; n++){
    int col = n0 + wn*64 + n*16 + (lane & 15);
    float bv = bg2[col];
    #pragma unroll
    for (int m = 0; m < 4; m++){
      int r0 = m0 + wm*64 + m*16 + ((lane >> 4) << 2);
      #pragma unroll
      for (int r = 0; r < 4; r++){
        size_t idx = (size_t)(r0 + r) * DM + col;
        float g = 1.0f / (1.0f + __expf(-(acc[m][n][r] + bv)));
        float lv = bf2f(lin[idx]), wv = bf2f(win[idx]);
        outc[idx] = f2bf(g * lv + (1.0f - g) * wv);
      }
    }
  }
}

// ---------------- final GEMM: outc . wo + bo + x -> fp32 out ----------------
__global__ __launch_bounds__(256) void kfinal(const u16* __restrict__ outc, const u16* __restrict__ woT,
                                              const float* __restrict__ bo, const float* __restrict__ x,
                                              float* __restrict__ out){
  __shared__ u16 ldsA[8192], ldsB[8192];
  int m0 = blockIdx.x << 7, n0 = blockIdx.y << 7;
  ZERO_ACC
  gemm_core<1>(outc, 0, 0, DM, woT, DM, DM, m0, n0, ldsA, ldsB, acc);
  EPI_COORDS
  #pragma unroll
  for (int n = 0; n < 4; n++){
    int col = n0 + wn*64 + n*16 + (lane & 15);
    float bv = bo[col];
    #pragma unroll
    for (int m = 0; m < 4; m++){
      int r0 = m0 + wm*64 + m*16 + ((lane >> 4) << 2);
      #pragma unroll
      for (int r = 0; r < 4; r++){
        size_t idx = (size_t)(r0 + r) * DM + col;
        out[idx] = acc[m][n][r] + bv + x[idx];
      }
    }
  }
}

extern "C" void kernel_launch(void* const* d_in, const int* in_sizes, int n_in,
                              void* d_out, int out_size, void* d_ws, size_t ws_size,
                              hipStream_t stream)
{
  const float* x      = (const float*)d_in[0];
  const float* wq_lin = (const float*)d_in[1];  const float* bq_lin = (const float*)d_in[2];
  const float* wk_lin = (const float*)d_in[3];  const float* bk_lin = (const float*)d_in[4];
  const float* wv_lin = (const float*)d_in[5];  const float* bv_lin = (const float*)d_in[6];
  const float* wq_loc = (const float*)d_in[7];  const float* bq_loc = (const float*)d_in[8];
  const float* wk_loc = (const float*)d_in[9];  const float* bk_loc = (const float*)d_in[10];
  const float* wv_loc = (const float*)d_in[11]; const float* bv_loc = (const float*)d_in[12];
  const float* wo     = (const float*)d_in[13]; const float* bo     = (const float*)d_in[14];
  const float* wg1    = (const float*)d_in[15]; const float* bg1    = (const float*)d_in[16];
  const float* wg2    = (const float*)d_in[17]; const float* bg2    = (const float*)d_in[18];
  const float* rel_bias = (const float*)d_in[19];
  const float* ln_g   = (const float*)d_in[20]; const float* ln_b   = (const float*)d_in[21];

  char* ws = (char*)d_ws;
  size_t off = 0;
  auto alloc = [&](size_t bytes) -> void* {
    void* p = ws + off;
    off += (bytes + 255) & ~(size_t)255;
    return p;
  };
  const size_t MB2 = (size_t)1024 * 1024 * 2;       // 1024x1024 bf16
  const size_t ACT = (size_t)4096 * 1024 * 2;       // [4096][1024] bf16
  u16* wT[6]; for (int i = 0; i < 6; i++) wT[i] = (u16*)alloc(MB2);
  u16* woT   = (u16*)alloc(MB2);
  u16* wg1T  = (u16*)alloc((size_t)1024 * 3072 * 2);
  u16* wg2T  = (u16*)alloc(MB2);
  u16* hbf   = (u16*)alloc(ACT);
  u16* phiQ  = (u16*)alloc(ACT);
  u16* phiKT = (u16*)alloc(ACT);
  u16* vT    = (u16*)alloc(ACT);
  u16* qloc  = (u16*)alloc(ACT);
  u16* kloc  = (u16*)alloc(ACT);
  u16* vloc  = (u16*)alloc(ACT);
  u16* kvT   = (u16*)alloc(2 * MB2);
  float* ksum = (float*)alloc(2 * 1024 * 4);
  float* dnm  = (float*)alloc(4096 * 4);
  u16* lin   = (u16*)alloc(ACT);
  u16* win   = (u16*)alloc(ACT);
  u16* g1    = phiQ;   // reuse: phiQ dead after knum
  u16* outc  = vT;     // reuse: vT dead after kkv

  dim3 blk(256);
  ktranspose<<<dim3(16,16), blk, 0, stream>>>(wq_lin, wT[0], 1024, 1024);
  ktranspose<<<dim3(16,16), blk, 0, stream>>>(wk_lin, wT[1], 1024, 1024);
  ktranspose<<<dim3(16,16), blk, 0, stream>>>(wv_lin, wT[2], 1024, 1024);
  ktranspose<<<dim3(16,16), blk, 0, stream>>>(wq_loc, wT[3], 1024, 1024);
  ktranspose<<<dim3(16,16), blk, 0, stream>>>(wk_loc, wT[4], 1024, 1024);
  ktranspose<<<dim3(16,16), blk, 0, stream>>>(wv_loc, wT[5], 1024, 1024);
  ktranspose<<<dim3(16,16), blk, 0, stream>>>(wo, woT, 1024, 1024);
  ktranspose<<<dim3(16,48), blk, 0, stream>>>(wg1, wg1T, 3072, 1024);
  ktranspose<<<dim3(16,16), blk, 0, stream>>>(wg2, wg2T, 1024, 1024);

  kln<<<4096, blk, 0, stream>>>(x, ln_g, ln_b, hbf);

  kqkv<<<dim3(32,48), blk, 0, stream>>>(hbf, wT[0], wT[1], wT[2], wT[3], wT[4], wT[5],
                                        bq_lin, bk_lin, bv_lin, bq_loc, bk_loc, bv_loc,
                                        phiQ, phiKT, vT, qloc, kloc, vloc);

  ksumk<<<2048, blk, 0, stream>>>(phiKT, ksum);
  kdenom<<<4096, blk, 0, stream>>>(phiQ, ksum, dnm);
  kkv<<<dim3(8,8,2), blk, 0, stream>>>(vT, phiKT, kvT);
  knum<<<dim3(16,8,2), blk, 0, stream>>>(phiQ, kvT, dnm, lin);

  kwin<<<dim3(32,16,2), blk, 0, stream>>>(qloc, kloc, vloc, rel_bias, win);

  kgate1<<<dim3(32,8), blk, 0, stream>>>(lin, win, hbf, wg1T, bg1, g1);
  kgate2<<<dim3(32,8), blk, 0, stream>>>(g1, wg2T, bg2, lin, win, outc);
  kfinal<<<dim3(32,8), blk, 0, stream>>>(outc, woT, bo, x, (float*)d_out);
}

// Round 2
// 317.387 us; speedup vs baseline: 1.0465x; 1.0465x over previous
//
#include <hip/hip_runtime.h>

typedef unsigned short u16;
typedef unsigned int u32;
typedef float f32x4 __attribute__((ext_vector_type(4)));
typedef __bf16 bf16x8 __attribute__((ext_vector_type(8)));

#define SEQ 2048
#define DM 1024

__device__ __forceinline__ float bf2f(u16 a){
  u32 b = ((u32)a) << 16; float f; __builtin_memcpy(&f, &b, 4); return f;
}
__device__ __forceinline__ u16 f2bf(float f){
  u32 b; __builtin_memcpy(&b, &f, 4);
  b += 0x7fffu + ((b >> 16) & 1u);
  return (u16)(b >> 16);
}

__device__ __forceinline__ void gload16(const void* g, void* l){
  __builtin_amdgcn_global_load_lds((const __attribute__((address_space(1))) u32*)g,
                                   (__attribute__((address_space(3))) u32*)l, 16, 0, 0);
}

// ---------------- fused weight convert+transpose: 9 matrices, one launch ----------------
struct TP { const float* src[9]; u16* dst[9]; int K[9]; };

__global__ __launch_bounds__(256) void ktransall(TP tp){
  __shared__ float tile[64][65];
  int z = blockIdx.z;
  int K = tp.K[z];
  int kb = blockIdx.y << 6, nb = blockIdx.x << 6;
  if (kb >= K) return;
  const float* W = tp.src[z];
  u16* WT = tp.dst[z];
  const int N = 1024;
  int t = threadIdx.x;
  #pragma unroll
  for (int i = 0; i < 4; i++){
    int idx = t + (i << 8);
    int r = idx >> 4, c = (idx & 15) << 2;
    float4 v = *(const float4*)(W + (size_t)(kb + r) * N + nb + c);
    tile[r][c] = v.x; tile[r][c+1] = v.y; tile[r][c+2] = v.z; tile[r][c+3] = v.w;
  }
  __syncthreads();
  #pragma unroll
  for (int i = 0; i < 2; i++){
    int idx = t + (i << 8);
    int n = idx >> 3, k8 = (idx & 7) << 3;
    union { u16 s[8]; int4 v; } u;
    #pragma unroll
    for (int j = 0; j < 8; j++) u.s[j] = f2bf(tile[k8 + j][n]);
    *(int4*)(WT + (size_t)(nb + n) * K + kb + k8) = u.v;
  }
}

// ---------------- layernorm: x f32 -> h bf16 ----------------
__global__ __launch_bounds__(256) void kln(const float* __restrict__ x, const float* __restrict__ gg,
                                           const float* __restrict__ bb, u16* __restrict__ h){
  int row = blockIdx.x, t = threadIdx.x;
  float4 xv = ((const float4*)(x + (size_t)row * DM))[t];
  float s  = xv.x + xv.y + xv.z + xv.w;
  float s2 = xv.x*xv.x + xv.y*xv.y + xv.z*xv.z + xv.w*xv.w;
  #pragma unroll
  for (int o = 1; o < 64; o <<= 1){ s += __shfl_xor(s, o); s2 += __shfl_xor(s2, o); }
  __shared__ float r1[4], r2[4];
  if ((t & 63) == 0){ r1[t >> 6] = s; r2[t >> 6] = s2; }
  __syncthreads();
  float S = r1[0]+r1[1]+r1[2]+r1[3], S2 = r2[0]+r2[1]+r2[2]+r2[3];
  float mu = S * (1.0f/DM);
  float var = S2 * (1.0f/DM) - mu*mu;
  float rstd = rsqrtf(var + 1e-5f);
  float4 gv = ((const float4*)gg)[t], bv = ((const float4*)bb)[t];
  ushort4 o;
  o.x = f2bf((xv.x - mu)*rstd*gv.x + bv.x);
  o.y = f2bf((xv.y - mu)*rstd*gv.y + bv.y);
  o.z = f2bf((xv.z - mu)*rstd*gv.z + bv.z);
  o.w = f2bf((xv.w - mu)*rstd*gv.w + bv.w);
  ((ushort4*)(h + (size_t)row * DM))[t] = o;
}

// ================= 256x256 8-wave 8-phase pipelined GEMM (kqkv only) =================
// C[4096][6144] = h[4096][1024] . W^T where W = 6 fused [1024][1024] bf16 (row = out col)
// LDS: A0(32K) A1(32K) B0(32K) B1(32K) = 128 KiB dynamic. buf parity = K-tile parity.
// Counted vmcnt(4) at phases 4/8 only; halves staged per deadness schedule.

__device__ __forceinline__ float phi_elu(float v){ return v > 0.f ? v + 1.f : __expf(v); }

#define SBAR  __builtin_amdgcn_sched_barrier(0); __builtin_amdgcn_s_barrier(); __builtin_amdgcn_sched_barrier(0);
#define LGKM0 asm volatile("s_waitcnt lgkmcnt(0)" ::: "memory"); __builtin_amdgcn_sched_barrier(0);
#define VM4   asm volatile("s_waitcnt vmcnt(4)" ::: "memory"); __builtin_amdgcn_sched_barrier(0);

__global__ __launch_bounds__(512, 2) void kqkv8(
  const u16* __restrict__ h,
  const u16* wt0, const u16* wt1, const u16* wt2, const u16* wt3, const u16* wt4, const u16* wt5,
  const float* b0, const float* b1, const float* b2, const float* b3, const float* b4, const float* b5,
  u16* phiQ, u16* phiKT, u16* vT, u16* qloc, u16* kloc, u16* vloc)
{
  extern __shared__ char smem[];
  char* A0 = smem;
  char* A1 = smem + 32768;
  char* B0 = smem + 65536;
  char* B1 = smem + 98304;

  const int t = threadIdx.x, lane = t & 63, w = t >> 6;
  const int wm = w >> 2, wn = w & 3;

  // XCD-aware swizzle: 384 blocks = 48 per XCD, contiguous chunks
  int bid = blockIdx.x;
  int swz = (bid & 7) * 48 + (bid >> 3);
  int mt = swz & 15, ntile = swz >> 4;
  int m0 = mt << 8;
  int n0g = ntile << 8;
  int wi = n0g >> 10;
  int n0 = n0g & 1023;
  const u16* Bp = wi==0?wt0: wi==1?wt1: wi==2?wt2: wi==3?wt3: wi==4?wt4: wt5;
  const float* bsel = wi==0?b0: wi==1?b1: wi==2?b2: wi==3?b3: wi==4?b4: b5;

  // stage one half-tile (128 rows x 64 k): 2 gload16 per thread
  auto STAGE = [&](char* ldsHalf, const u16* gsrc, int grow0, int ktile){
    #pragma unroll
    for (int j = 0; j < 2; j++){
      int r = (w << 4) + (j << 3) + (lane >> 3);          // 0..127 in half
      int csw = ((lane & 7) << 4) ^ ((r & 7) << 4);       // pre-swizzled src byte col
      gload16((const char*)(gsrc + (size_t)(grow0 + r) * 1024 + ktile * 64) + csw,
              ldsHalf + (((w << 4) + (j << 3)) << 7));    // wave-uniform dst, +lane*16 by HW
    }
  };
  auto LDA = [&](const char* ab, int m, int kk) -> bf16x8 {
    int ra = (wm << 7) + (m << 4) + (lane & 15);
    return *(const bf16x8*)(ab + (ra << 7) + (((kk << 6) + ((lane >> 4) << 4)) ^ ((ra & 7) << 4)));
  };
  auto LDB = [&](const char* bb, int n, int kk) -> bf16x8 {
    int rb = (wn << 6) + (n << 4) + (lane & 15);
    return *(const bf16x8*)(bb + (rb << 7) + (((kk << 6) + ((lane >> 4) << 4)) ^ ((rb & 7) << 4)));
  };

  f32x4 acc[8][4];
  #pragma unroll
  for (int m = 0; m < 8; m++)
    #pragma unroll
    for (int n = 0; n < 4; n++) acc[m][n] = (f32x4){0.f,0.f,0.f,0.f};

  const int NT = 16;  // K=1024 / 64
  // prologue: tile0 (B0h0,B0h1,A0h0,A0h1), tile1 (B1h0,B1h1) = 12 loads
  STAGE(B0,         Bp, n0,       0);
  STAGE(B0 + 16384, Bp, n0 + 128, 0);
  STAGE(A0,         h,  m0,       0);
  STAGE(A0 + 16384, h,  m0 + 128, 0);
  STAGE(B1,         Bp, n0,       1);
  STAGE(B1 + 16384, Bp, n0 + 128, 1);
  VM4                      // tile0 fully resident; tile1 B halves in flight
  SBAR

#define MFMA_Q(AF, BF, MO, NO) \
  __builtin_amdgcn_s_setprio(1); \
  _Pragma("unroll") for (int m_ = 0; m_ < 4; m_++) \
  _Pragma("unroll") for (int n_ = 0; n_ < 2; n_++) \
  _Pragma("unroll") for (int k_ = 0; k_ < 2; k_++) \
    acc[(MO)+m_][(NO)+n_] = __builtin_amdgcn_mfma_f32_16x16x32_bf16(AF[m_][k_], BF[n_][k_], acc[(MO)+m_][(NO)+n_], 0,0,0); \
  __builtin_amdgcn_s_setprio(0);

  // one 4-phase group: consume (cA,cB); write A halves of tile tA into wA, B halves of tile tB into wB
#define GROUP(cA, cB, wA, tA, wB, tB) { \
    bf16x8 af[4][2], bf01[2][2], bf23[2][2]; \
    /* ph1 */ \
    _Pragma("unroll") for (int m_ = 0; m_ < 4; m_++){ af[m_][0] = LDA(cA, m_, 0); af[m_][1] = LDA(cA, m_, 1); } \
    _Pragma("unroll") for (int n_ = 0; n_ < 2; n_++){ bf01[n_][0] = LDB(cB, n_, 0); bf01[n_][1] = LDB(cB, n_, 1); } \
    STAGE(wA, h_is_A ? h : h, m0, tA); /* placeholder replaced below */ \
  }
  // (GROUP macro above unused — expanded explicitly for clarity/safety)
#undef GROUP

  #pragma unroll 1
  for (int i = 0; i < NT/2; i++){
    int t1 = 2*i + 1;
    int t2 = 2*i + 2 < NT ? 2*i + 2 : NT - 1;
    int t3 = 2*i + 3 < NT ? 2*i + 3 : NT - 1;
    // ---- group A: consume tiles 2i from (A0,B0) ----
    {
      bf16x8 af[4][2], bf01[2][2], bf23[2][2];
      // ph1: read A m0-3 + B n0-1; stage tile(2i+1).Ah0 -> A1h0
      #pragma unroll
      for (int m = 0; m < 4; m++){ af[m][0] = LDA(A0, m, 0); af[m][1] = LDA(A0, m, 1); }
      #pragma unroll
      for (int n = 0; n < 2; n++){ bf01[n][0] = LDB(B0, n, 0); bf01[n][1] = LDB(B0, n, 1); }
      STAGE(A1, h, m0, t1);
      SBAR LGKM0
      MFMA_Q(af, bf01, 0, 0)
      SBAR
      // ph2: read B n2-3; stage tile(2i+1).Ah1 -> A1h1
      #pragma unroll
      for (int n = 0; n < 2; n++){ bf23[n][0] = LDB(B0, n + 2, 0); bf23[n][1] = LDB(B0, n + 2, 1); }
      STAGE(A1 + 16384, h, m0 + 128, t1);
      SBAR LGKM0
      MFMA_Q(af, bf23, 0, 2)
      SBAR
      // ph3: read A m4-7; stage tile(t2).Bh0 -> B0h0 (dead after ph2)
      #pragma unroll
      for (int m = 0; m < 4; m++){ af[m][0] = LDA(A0, m + 4, 0); af[m][1] = LDA(A0, m + 4, 1); }
      STAGE(B0, Bp, n0, t2);
      SBAR LGKM0
      MFMA_Q(af, bf01, 4, 0)
      SBAR
      // ph4: stage tile(t2).Bh1 -> B0h1; counted vmcnt -> tile 2i+1 fully resident
      STAGE(B0 + 16384, Bp, n0 + 128, t2);
      VM4
      SBAR
      MFMA_Q(af, bf23, 4, 2)
      SBAR
    }
    // ---- group B: consume tile 2i+1 from (A1,B1) ----
    {
      bf16x8 af[4][2], bf01[2][2], bf23[2][2];
      // ph5: read; stage tile(t2).Ah0 -> A0h0 (dead after ph3)
      #pragma unroll
      for (int m = 0; m < 4; m++){ af[m][0] = LDA(A1, m, 0); af[m][1] = LDA(A1, m, 1); }
      #pragma unroll
      for (int n = 0; n < 2; n++){ bf01[n][0] = LDB(B1, n, 0); bf01[n][1] = LDB(B1, n, 1); }
      STAGE(A0, h, m0, t2);
      SBAR LGKM0
      MFMA_Q(af, bf01, 0, 0)
      SBAR
      // ph6: stage tile(t2).Ah1 -> A0h1
      #pragma unroll
      for (int n = 0; n < 2; n++){ bf23[n][0] = LDB(B1, n + 2, 0); bf23[n][1] = LDB(B1, n + 2, 1); }
      STAGE(A0 + 16384, h, m0 + 128, t2);
      SBAR LGKM0
      MFMA_Q(af, bf23, 0, 2)
      SBAR
      // ph7: stage tile(t3).Bh0 -> B1h0 (dead after ph6)
      #pragma unroll
      for (int m = 0; m < 4; m++){ af[m][0] = LDA(A1, m + 4, 0); af[m][1] = LDA(A1, m + 4, 1); }
      STAGE(B1, Bp, n0, t3);
      SBAR LGKM0
      MFMA_Q(af, bf01, 4, 0)
      SBAR
      // ph8: stage tile(t3).Bh1 -> B1h1; counted vmcnt -> tile t2 fully resident
      STAGE(B1 + 16384, Bp, n0 + 128, t3);
      VM4
      SBAR
      MFMA_Q(af, bf23, 4, 2)
      SBAR
    }
  }

  // epilogue
  #pragma unroll
  for (int n = 0; n < 4; n++){
    int col = n0 + (wn << 6) + (n << 4) + (lane & 15);
    float bv = bsel[col];
    #pragma unroll
    for (int m = 0; m < 8; m++){
      int r0 = m0 + (wm << 7) + (m << 4) + ((lane >> 4) << 2);
      float e[4];
      #pragma unroll
      for (int r = 0; r < 4; r++) e[r] = acc[m][n][r] + bv;
      if (wi == 0){
        #pragma unroll
        for (int r = 0; r < 4; r++) phiQ[(size_t)(r0 + r) * DM + col] = f2bf(phi_elu(e[r]));
      } else if (wi == 1 || wi == 2){
        union { u16 s[4]; ushort4 v; } o;
        #pragma unroll
        for (int r = 0; r < 4; r++) o.s[r] = f2bf(wi == 1 ? phi_elu(e[r]) : e[r]);
        int bb = r0 >> 11, sl = r0 & 2047;
        u16* dst = (wi == 1) ? phiKT : vT;
        *(ushort4*)(dst + ((size_t)(bb << 10) + col) * SEQ + sl) = o.v;
      } else {
        u16* dst = wi==3 ? qloc : wi==4 ? kloc : vloc;
        #pragma unroll
        for (int r = 0; r < 4; r++) dst[(size_t)(r0 + r) * DM + col] = f2bf(e[r]);
      }
    }
  }
}

// ---------------- 128x128 m97-style GEMM core (N=1024 GEMMs) ----------------
template<int NCHUNK>
__device__ __forceinline__ void gemm_core(const u16* A0, const u16* A1, const u16* A2, int lda,
                                          const u16* B, int ldb, int K, int m0, int n0,
                                          u16* ldsA, u16* ldsB, f32x4 (&acc)[4][4])
{
  const int t = threadIdx.x, lane = t & 63, w = t >> 6;
  const int wm = w >> 1, wn = w & 1;
  int srow[4], scol[4];
  #pragma unroll
  for (int j = 0; j < 4; j++){
    int r = ((w << 2) + j) * 8 + (lane >> 3);
    int csw = (lane & 7) << 4;
    srow[j] = r;
    scol[j] = csw ^ ((r & 7) << 4);
  }
  for (int k0 = 0; k0 < K; k0 += 64){
    const u16* Ab;
    if (NCHUNK == 3){
      int ci = k0 >> 10;
      const u16* cp = (ci == 0) ? A0 : ((ci == 1) ? A1 : A2);
      Ab = cp + (k0 & 1023);
    } else {
      Ab = A0 + k0;
    }
    const u16* Bb = B + k0;
    #pragma unroll
    for (int j = 0; j < 4; j++){
      gload16((const char*)(Ab + (size_t)(m0 + srow[j]) * lda) + scol[j],
              (char*)ldsA + (((w << 2) + j) << 10));
      gload16((const char*)(Bb + (size_t)(n0 + srow[j]) * ldb) + scol[j],
              (char*)ldsB + (((w << 2) + j) << 10));
    }
    __syncthreads();
    #pragma unroll
    for (int kk = 0; kk < 2; kk++){
      bf16x8 a[4], b[4];
      #pragma unroll
      for (int m = 0; m < 4; m++){
        int ra = wm*64 + m*16 + (lane & 15);
        int byt = ra*128 + (((kk << 6) + ((lane >> 4) << 4)) ^ ((ra & 7) << 4));
        a[m] = *(const bf16x8*)((const char*)ldsA + byt);
      }
      #pragma unroll
      for (int n = 0; n < 4; n++){
        int rb = wn*64 + n*16 + (lane & 15);
        int byt = rb*128 + (((kk << 6) + ((lane >> 4) << 4)) ^ ((rb & 7) << 4));
        b[n] = *(const bf16x8*)((const char*)ldsB + byt);
      }
      #pragma unroll
      for (int m = 0; m < 4; m++)
        #pragma unroll
        for (int n = 0; n < 4; n++)
          acc[m][n] = __builtin_amdgcn_mfma_f32_16x16x32_bf16(a[m], b[n], acc[m][n], 0, 0, 0);
    }
    __syncthreads();
  }
}

#define EPI_COORDS \
  const int lane = threadIdx.x & 63, w = threadIdx.x >> 6; \
  const int wm = w >> 1, wn = w & 1;

#define ZERO_ACC f32x4 acc[4][4]; \
  _Pragma("unroll") for (int m = 0; m < 4; m++) _Pragma("unroll") for (int n = 0; n < 4; n++) acc[m][n] = (f32x4){0.f,0.f,0.f,0.f};

// ---------------- kv^T = v^T . phiK^T  (per batch) ----------------
__global__ __launch_bounds__(256) void kkv(const u16* __restrict__ vT, const u16* __restrict__ phiKT,
                                           u16* __restrict__ kvT){
  __shared__ u16 ldsA[8192], ldsB[8192];
  int b = blockIdx.z;
  int m0 = blockIdx.x << 7, n0 = blockIdx.y << 7;
  const u16* A = vT + (size_t)b * DM * SEQ;
  const u16* B = phiKT + (size_t)b * DM * SEQ;
  ZERO_ACC
  gemm_core<1>(A, 0, 0, SEQ, B, SEQ, SEQ, m0, n0, ldsA, ldsB, acc);
  EPI_COORDS
  u16* C = kvT + (size_t)b * DM * DM;
  #pragma unroll
  for (int n = 0; n < 4; n++){
    int col = n0 + wn*64 + n*16 + (lane & 15);
    #pragma unroll
    for (int m = 0; m < 4; m++){
      int r0 = m0 + wm*64 + m*16 + ((lane >> 4) << 2);
      #pragma unroll
      for (int r = 0; r < 4; r++) C[(size_t)(r0 + r) * DM + col] = f2bf(acc[m][n][r]);
    }
  }
}

// ---------------- num = phiQ . kv^T, lin = num / (denom + 1e-6) ----------------
__global__ __launch_bounds__(256) void knum(const u16* __restrict__ phiQ, const u16* __restrict__ kvT,
                                            const float* __restrict__ dn, u16* __restrict__ lin){
  __shared__ u16 ldsA[8192], ldsB[8192];
  int b = blockIdx.z;
  int m0 = blockIdx.x << 7, n0 = blockIdx.y << 7;
  const u16* A = phiQ + (size_t)b * SEQ * DM;
  const u16* B = kvT + (size_t)b * DM * DM;
  ZERO_ACC
  gemm_core<1>(A, 0, 0, DM, B, DM, DM, m0, n0, ldsA, ldsB, acc);
  EPI_COORDS
  #pragma unroll
  for (int n = 0; n < 4; n++){
    int col = n0 + wn*64 + n*16 + (lane & 15);
    #pragma unroll
    for (int m = 0; m < 4; m++){
      int r0 = m0 + wm*64 + m*16 + ((lane >> 4) << 2);
      #pragma unroll
      for (int r = 0; r < 4; r++){
        float d = dn[(b << 11) + r0 + r] + 1e-6f;
        lin[((size_t)(b << 11) + r0 + r) * DM + col] = f2bf(acc[m][n][r] / d);
      }
    }
  }
}

// ---------------- ksum[b][d] = sum_s phiKT[b][d][s] ----------------
__global__ __launch_bounds__(256) void ksumk(const u16* __restrict__ kt, float* __restrict__ ks){
  int row = blockIdx.x, t = threadIdx.x;
  const ushort4* src = (const ushort4*)(kt + (size_t)row * SEQ);
  float s = 0.f;
  for (int i = t; i < 512; i += 256){
    ushort4 v = src[i];
    s += bf2f(v.x) + bf2f(v.y) + bf2f(v.z) + bf2f(v.w);
  }
  #pragma unroll
  for (int o = 1; o < 64; o <<= 1) s += __shfl_xor(s, o);
  __shared__ float red[4];
  if ((t & 63) == 0) red[t >> 6] = s;
  __syncthreads();
  if (t == 0) ks[row] = red[0] + red[1] + red[2] + red[3];
}

// ---------------- denom[row] = phiQ[row] . ksum[b] ----------------
__global__ __launch_bounds__(256) void kdenom(const u16* __restrict__ phiQ, const float* __restrict__ ks,
                                              float* __restrict__ dn){
  int row = blockIdx.x, t = threadIdx.x;
  ushort4 v = ((const ushort4*)(phiQ + (size_t)row * DM))[t];
  float4 kk = ((const float4*)(ks + ((size_t)(row >> 11) << 10)))[t];
  float s = bf2f(v.x)*kk.x + bf2f(v.y)*kk.y + bf2f(v.z)*kk.z + bf2f(v.w)*kk.w;
  #pragma unroll
  for (int o = 1; o < 64; o <<= 1) s += __shfl_xor(s, o);
  __shared__ float red[4];
  if ((t & 63) == 0) red[t >> 6] = s;
  __syncthreads();
  if (t == 0) dn[row] = red[0] + red[1] + red[2] + red[3];
}

// ---------------- sliding-window attention ----------------
__global__ __launch_bounds__(256) void kwin(const u16* __restrict__ qloc, const u16* __restrict__ kloc,
                                            const u16* __restrict__ vloc, const float* __restrict__ rel_bias,
                                            u16* __restrict__ wout)
{
  __shared__ float KV[128 * 68];
  __shared__ float Ssm[64 * 84];
  __shared__ float bias_s[65];
  int qt = blockIdx.x, hh = blockIdx.y, b = blockIdx.z;
  int q0 = qt << 6;
  int t = threadIdx.x;
  int q = t >> 2, sub = t & 3, qq = q & 15;
  size_t base = (size_t)b * SEQ * DM + hh * 64;
  for (int i = t; i < 1024; i += 256){
    int r = i >> 3, seg = i & 7;
    int p = q0 + r - 32;
    float* dst = &KV[r * 68 + (seg << 3)];
    if ((unsigned)p < SEQ){
      int4 raw = *(const int4*)(kloc + base + (size_t)p * DM + (seg << 3));
      const u16* s = (const u16*)&raw;
      #pragma unroll
      for (int j = 0; j < 8; j++) dst[j] = bf2f(s[j]);
    } else {
      #pragma unroll
      for (int j = 0; j < 8; j++) dst[j] = 0.f;
    }
  }
  if (t < 65) bias_s[t] = rel_bias[(t + 32) * 16 + hh];
  float qreg[16];
  {
    const u16* qp = qloc + base + (size_t)(q0 + q) * DM + (sub << 4);
    int4 raw0 = *(const int4*)qp;
    int4 raw1 = *(const int4*)(qp + 8);
    const u16* s0 = (const u16*)&raw0; const u16* s1 = (const u16*)&raw1;
    #pragma unroll
    for (int j = 0; j < 8; j++){ qreg[j] = bf2f(s0[j]); qreg[8 + j] = bf2f(s1[j]); }
  }
  __syncthreads();
  int rlo = (t >> 6) << 4;
  for (int rr = 0; rr < 80; rr++){
    int r = rlo + rr;
    const float* kr = &KV[r * 68 + (sub << 4)];
    float s = 0.f;
    #pragma unroll
    for (int i = 0; i < 16; i++) s += qreg[i] * kr[i];
    s += __shfl_xor(s, 1); s += __shfl_xor(s, 2);
    int wrel = r - q;
    int p = q0 + r - 32;
    float sc = -1e30f;
    if ((unsigned)wrel <= 64u && (unsigned)p < SEQ) sc = s * 0.125f + bias_s[wrel];
    if (sub == 0) Ssm[q * 84 + rr] = sc;
  }
  __syncthreads();
  for (int i = t; i < 1024; i += 256){
    int r = i >> 3, seg = i & 7;
    int p = q0 + r - 32;
    float* dst = &KV[r * 68 + (seg << 3)];
    if ((unsigned)p < SEQ){
      int4 raw = *(const int4*)(vloc + base + (size_t)p * DM + (seg << 3));
      const u16* s = (const u16*)&raw;
      #pragma unroll
      for (int j = 0; j < 8; j++) dst[j] = bf2f(s[j]);
    } else {
      #pragma unroll
      for (int j = 0; j < 8; j++) dst[j] = 0.f;
    }
  }
  float mloc = -1e30f;
  for (int wrel = sub; wrel <= 64; wrel += 4) mloc = fmaxf(mloc, Ssm[q * 84 + qq + wrel]);
  mloc = fmaxf(mloc, __shfl_xor(mloc, 1));
  mloc = fmaxf(mloc, __shfl_xor(mloc, 2));
  float lloc = 0.f;
  for (int wrel = sub; wrel <= 64; wrel += 4) lloc += __expf(Ssm[q * 84 + qq + wrel] - mloc);
  lloc += __shfl_xor(lloc, 1); lloc += __shfl_xor(lloc, 2);
  float inv = 1.0f / lloc;
  for (int wrel = sub; wrel <= 64; wrel += 4)
    Ssm[q * 84 + qq + wrel] = __expf(Ssm[q * 84 + qq + wrel] - mloc) * inv;
  __syncthreads();
  float accv[16];
  #pragma unroll
  for (int i = 0; i < 16; i++) accv[i] = 0.f;
  for (int rr = 0; rr < 80; rr++){
    int r = rlo + rr;
    float pv = Ssm[q * 84 + rr];
    pv = ((unsigned)(r - q) <= 64u) ? pv : 0.f;
    const float* vr = &KV[r * 68 + (sub << 4)];
    #pragma unroll
    for (int i = 0; i < 16; i++) accv[i] += pv * vr[i];
  }
  union { u16 s[16]; int4 v[2]; } ob;
  #pragma unroll
  for (int i = 0; i < 16; i++) ob.s[i] = f2bf(accv[i]);
  u16* dst = wout + base + (size_t)(q0 + q) * DM + (sub << 4);
  *(int4*)dst = ob.v[0];
  *(int4*)(dst + 8) = ob.v[1];
}

// ---------------- gate GEMM 1: relu([lin,win,h] . wg1 + bg1) ----------------
__global__ __launch_bounds__(256) void kgate1(const u16* __restrict__ lin, const u16* __restrict__ win,
                                              const u16* __restrict__ h, const u16* __restrict__ wg1T,
                                              const float* __restrict__ bg1, u16* __restrict__ g1){
  __shared__ u16 ldsA[8192], ldsB[8192];
  int m0 = blockIdx.x << 7, n0 = blockIdx.y << 7;
  ZERO_ACC
  gemm_core<3>(lin, win, h, DM, wg1T, 3072, 3072, m0, n0, ldsA, ldsB, acc);
  EPI_COORDS
  #pragma unroll
  for (int n = 0; n < 4; n++){
    int col = n0 + wn*64 + n*16 + (lane & 15);
    float bv = bg1[col];
    #pragma unroll
    for (int m = 0; m < 4; m++){
      int r0 = m0 + wm*64 + m*16 + ((lane >> 4) << 2);
      #pragma unroll
      for (int r = 0; r < 4; r++){
        float v = acc[m][n][r] + bv;
        g1[(size_t)(r0 + r) * DM + col] = f2bf(v > 0.f ? v : 0.f);
      }
    }
  }
}

// ---------------- gate GEMM 2 + sigmoid + convex combine ----------------
__global__ __launch_bounds__(256) void kgate2(const u16* __restrict__ g1, const u16* __restrict__ wg2T,
                                              const float* __restrict__ bg2, const u16* __restrict__ lin,
                                              const u16* __restrict__ win, u16* __restrict__ outc){
  __shared__ u16 ldsA[8192], ldsB[8192];
  int m0 = blockIdx.x << 7, n0 = blockIdx.y << 7;
  ZERO_ACC
  gemm_core<1>(g1, 0, 0, DM, wg2T, DM, DM, m0, n0, ldsA, ldsB, acc);
  EPI_COORDS
  #pragma unroll
  for (int n = 0; n < 4; n++){
    int col = n0 + wn*64 + n*16 + (lane & 15);
    float bv = bg2[col];
    #pragma unroll
    for (int m = 0; m < 4; m++){
      int r0 = m0 + wm*64 + m*16 + ((lane >> 4) << 2);
      #pragma unroll
      for (int r = 0; r < 4; r++){
        size_t idx = (size_t)(r0 + r) * DM + col;
        float g = 1.0f / (1.0f + __expf(-(acc[m][n][r] + bv)));
        float lv = bf2f(lin[idx]), wv = bf2f(win[idx]);
        outc[idx] = f2bf(g * lv + (1.0f - g) * wv);
      }
    }
  }
}

// ---------------- final GEMM: outc . wo + bo + x -> fp32 out ----------------
__global__ __launch_bounds__(256) void kfinal(const u16* __restrict__ outc, const u16* __restrict__ woT,
                                              const float* __restrict__ bo, const float* __restrict__ x,
                                              float* __restrict__ out){
  __shared__ u16 ldsA[8192], ldsB[8192];
  int m0 = blockIdx.x << 7, n0 = blockIdx.y << 7;
  ZERO_ACC
  gemm_core<1>(outc, 0, 0, DM, woT, DM, DM, m0, n0, ldsA, ldsB, acc);
  EPI_COORDS
  #pragma unroll
  for (int n = 0; n < 4; n++){
    int col = n0 + wn*64 + n*16 + (lane & 15);
    float bv = bo[col];
    #pragma unroll
    for (int m = 0; m < 4; m++){
      int r0 = m0 + wm*64 + m*16 + ((lane >> 4) << 2);
      #pragma unroll
      for (int r = 0; r < 4; r++){
        size_t idx = (size_t)(r0 + r) * DM + col;
        out[idx] = acc[m][n][r] + bv + x[idx];
      }
    }
  }
}

extern "C" void kernel_launch(void* const* d_in, const int* in_sizes, int n_in,
                              void* d_out, int out_size, void* d_ws, size_t ws_size,
                              hipStream_t stream)
{
  const float* x      = (const float*)d_in[0];
  const float* wq_lin = (const float*)d_in[1];  const float* bq_lin = (const float*)d_in[2];
  const float* wk_lin = (const float*)d_in[3];  const float* bk_lin = (const float*)d_in[4];
  const float* wv_lin = (const float*)d_in[5];  const float* bv_lin = (const float*)d_in[6];
  const float* wq_loc = (const float*)d_in[7];  const float* bq_loc = (const float*)d_in[8];
  const float* wk_loc = (const float*)d_in[9];  const float* bk_loc = (const float*)d_in[10];
  const float* wv_loc = (const float*)d_in[11]; const float* bv_loc = (const float*)d_in[12];
  const float* wo     = (const float*)d_in[13]; const float* bo     = (const float*)d_in[14];
  const float* wg1    = (const float*)d_in[15]; const float* bg1    = (const float*)d_in[16];
  const float* wg2    = (const float*)d_in[17]; const float* bg2    = (const float*)d_in[18];
  const float* rel_bias = (const float*)d_in[19];
  const float* ln_g   = (const float*)d_in[20]; const float* ln_b   = (const float*)d_in[21];

  char* ws = (char*)d_ws;
  size_t off = 0;
  auto alloc = [&](size_t bytes) -> void* {
    void* p = ws + off;
    off += (bytes + 255) & ~(size_t)255;
    return p;
  };
  const size_t MB2 = (size_t)1024 * 1024 * 2;
  const size_t ACT = (size_t)4096 * 1024 * 2;
  u16* wT[6]; for (int i = 0; i < 6; i++) wT[i] = (u16*)alloc(MB2);
  u16* woT   = (u16*)alloc(MB2);
  u16* wg1T  = (u16*)alloc((size_t)1024 * 3072 * 2);
  u16* wg2T  = (u16*)alloc(MB2);
  u16* hbf   = (u16*)alloc(ACT);
  u16* phiQ  = (u16*)alloc(ACT);
  u16* phiKT = (u16*)alloc(ACT);
  u16* vT    = (u16*)alloc(ACT);
  u16* qloc  = (u16*)alloc(ACT);
  u16* kloc  = (u16*)alloc(ACT);
  u16* vloc  = (u16*)alloc(ACT);
  u16* kvT   = (u16*)alloc(2 * MB2);
  float* ksum = (float*)alloc(2 * 1024 * 4);
  float* dnm  = (float*)alloc(4096 * 4);
  u16* lin   = (u16*)alloc(ACT);
  u16* win   = (u16*)alloc(ACT);
  u16* g1    = phiQ;   // reuse: phiQ dead after knum
  u16* outc  = vT;     // reuse: vT dead after kkv

  // opt-in to 128 KiB dynamic LDS for kqkv8 (host-side attr set; capture-safe)
  hipFuncSetAttribute((const void*)kqkv8, hipFuncAttributeMaxDynamicSharedMemorySize, 131072);

  dim3 blk(256);
  TP tp;
  tp.src[0]=wq_lin; tp.src[1]=wk_lin; tp.src[2]=wv_lin; tp.src[3]=wq_loc; tp.src[4]=wk_loc;
  tp.src[5]=wv_loc; tp.src[6]=wo; tp.src[7]=wg1; tp.src[8]=wg2;
  tp.dst[0]=wT[0]; tp.dst[1]=wT[1]; tp.dst[2]=wT[2]; tp.dst[3]=wT[3]; tp.dst[4]=wT[4];
  tp.dst[5]=wT[5]; tp.dst[6]=woT; tp.dst[7]=wg1T; tp.dst[8]=wg2T;
  for (int i = 0; i < 9; i++) tp.K[i] = (i == 7) ? 3072 : 1024;
  ktransall<<<dim3(16,48,9), blk, 0, stream>>>(tp);

  kln<<<4096, blk, 0, stream>>>(x, ln_g, ln_b, hbf);

  kqkv8<<<384, 512, 131072, stream>>>(hbf, wT[0], wT[1], wT[2], wT[3], wT[4], wT[5],
                                      bq_lin, bk_lin, bv_lin, bq_loc, bk_loc, bv_loc,
                                      phiQ, phiKT, vT, qloc, kloc, vloc);

  ksumk<<<2048, blk, 0, stream>>>(phiKT, ksum);
  kdenom<<<4096, blk, 0, stream>>>(phiQ, ksum, dnm);
  kkv<<<dim3(8,8,2), blk, 0, stream>>>(vT, phiKT, kvT);
  knum<<<dim3(16,8,2), blk, 0, stream>>>(phiQ, kvT, dnm, lin);

  kwin<<<dim3(32,16,2), blk, 0, stream>>>(qloc, kloc, vloc, rel_bias, win);

  kgate1<<<dim3(32,8), blk, 0, stream>>>(lin, win, hbf, wg1T, bg1, g1);
  kgate2<<<dim3(32,8), blk, 0, stream>>>(g1, wg2T, bg2, lin, win, outc);
  kfinal<<<dim3(32,8), blk, 0, stream>>>(outc, woT, bo, x, (float*)d_out);
}

// Round 3
// 316.166 us; speedup vs baseline: 1.0505x; 1.0039x over previous
//
#include <hip/hip_runtime.h>

typedef unsigned short u16;
typedef unsigned int u32;
typedef float f32x4 __attribute__((ext_vector_type(4)));
typedef __bf16 bf16x8 __attribute__((ext_vector_type(8)));

#define SEQ 2048
#define DM 1024

__device__ __forceinline__ float bf2f(u16 a){
  u32 b = ((u32)a) << 16; float f; __builtin_memcpy(&f, &b, 4); return f;
}
__device__ __forceinline__ u16 f2bf(float f){
  u32 b; __builtin_memcpy(&b, &f, 4);
  b += 0x7fffu + ((b >> 16) & 1u);
  return (u16)(b >> 16);
}

__device__ __forceinline__ void gload16(const void* g, void* l){
  __builtin_amdgcn_global_load_lds((const __attribute__((address_space(1))) u32*)g,
                                   (__attribute__((address_space(3))) u32*)l, 16, 0, 0);
}

// ---------------- fused weight convert+transpose: 9 matrices, one launch ----------------
struct TP { const float* src[9]; u16* dst[9]; int K[9]; };

__global__ __launch_bounds__(256) void ktransall(TP tp){
  __shared__ float tile[64][65];
  int z = blockIdx.z;
  int K = tp.K[z];
  int kb = blockIdx.y << 6, nb = blockIdx.x << 6;
  if (kb >= K) return;
  const float* W = tp.src[z];
  u16* WT = tp.dst[z];
  const int N = 1024;
  int t = threadIdx.x;
  #pragma unroll
  for (int i = 0; i < 4; i++){
    int idx = t + (i << 8);
    int r = idx >> 4, c = (idx & 15) << 2;
    float4 v = *(const float4*)(W + (size_t)(kb + r) * N + nb + c);
    tile[r][c] = v.x; tile[r][c+1] = v.y; tile[r][c+2] = v.z; tile[r][c+3] = v.w;
  }
  __syncthreads();
  #pragma unroll
  for (int i = 0; i < 2; i++){
    int idx = t + (i << 8);
    int n = idx >> 3, k8 = (idx & 7) << 3;
    union { u16 s[8]; int4 v; } u;
    #pragma unroll
    for (int j = 0; j < 8; j++) u.s[j] = f2bf(tile[k8 + j][n]);
    *(int4*)(WT + (size_t)(nb + n) * K + kb + k8) = u.v;
  }
}

// ---------------- layernorm: x f32 -> h bf16 ----------------
__global__ __launch_bounds__(256) void kln(const float* __restrict__ x, const float* __restrict__ gg,
                                           const float* __restrict__ bb, u16* __restrict__ h){
  int row = blockIdx.x, t = threadIdx.x;
  float4 xv = ((const float4*)(x + (size_t)row * DM))[t];
  float s  = xv.x + xv.y + xv.z + xv.w;
  float s2 = xv.x*xv.x + xv.y*xv.y + xv.z*xv.z + xv.w*xv.w;
  #pragma unroll
  for (int o = 1; o < 64; o <<= 1){ s += __shfl_xor(s, o); s2 += __shfl_xor(s2, o); }
  __shared__ float r1[4], r2[4];
  if ((t & 63) == 0){ r1[t >> 6] = s; r2[t >> 6] = s2; }
  __syncthreads();
  float S = r1[0]+r1[1]+r1[2]+r1[3], S2 = r2[0]+r2[1]+r2[2]+r2[3];
  float mu = S * (1.0f/DM);
  float var = S2 * (1.0f/DM) - mu*mu;
  float rstd = rsqrtf(var + 1e-5f);
  float4 gv = ((const float4*)gg)[t], bv = ((const float4*)bb)[t];
  ushort4 o;
  o.x = f2bf((xv.x - mu)*rstd*gv.x + bv.x);
  o.y = f2bf((xv.y - mu)*rstd*gv.y + bv.y);
  o.z = f2bf((xv.z - mu)*rstd*gv.z + bv.z);
  o.w = f2bf((xv.w - mu)*rstd*gv.w + bv.w);
  ((ushort4*)(h + (size_t)row * DM))[t] = o;
}

// ================= 128x256-tile 8-wave pipelined GEMM for QKV =================
// C[4096][6144] = h[4096][1024] . W^T (6 fused [1024][1024] bf16 weights, row = out col)
// LDS: A0,A1 = 16K each (128x64), B0,B1 = 32K each (256x64) -> 96 KiB, 1 block/CU.
// Grid 768 = 3 blocks/CU exactly (no tail). 4 single-barrier phases per 2 K-tiles,
// counted vmcnt(2) at end of P2/P4 (before the barrier). Never vmcnt(0) in-loop.

__device__ __forceinline__ float phi_elu(float v){ return v > 0.f ? v + 1.f : __expf(v); }

#define SBAR  __builtin_amdgcn_sched_barrier(0); __builtin_amdgcn_s_barrier(); __builtin_amdgcn_sched_barrier(0);
#define LGKM0 asm volatile("s_waitcnt lgkmcnt(0)" ::: "memory"); __builtin_amdgcn_sched_barrier(0);
#define VM2   asm volatile("s_waitcnt vmcnt(2)" ::: "memory"); __builtin_amdgcn_sched_barrier(0);
#define VM0   asm volatile("s_waitcnt vmcnt(0)" ::: "memory"); __builtin_amdgcn_sched_barrier(0);

#define MFMA8x2(AF, BF, NOFF) \
  __builtin_amdgcn_s_setprio(1); \
  _Pragma("unroll") for (int m_ = 0; m_ < 4; m_++) \
  _Pragma("unroll") for (int n_ = 0; n_ < 2; n_++) \
  _Pragma("unroll") for (int k_ = 0; k_ < 2; k_++) \
    acc[m_][(NOFF)+n_] = __builtin_amdgcn_mfma_f32_16x16x32_bf16(AF[m_][k_], BF[n_][k_], acc[m_][(NOFF)+n_], 0,0,0); \
  __builtin_amdgcn_s_setprio(0);

__global__ __launch_bounds__(512, 2) void kqkv8(
  const u16* __restrict__ h,
  const u16* wt0, const u16* wt1, const u16* wt2, const u16* wt3, const u16* wt4, const u16* wt5,
  const float* b0, const float* b1, const float* b2, const float* b3, const float* b4, const float* b5,
  u16* phiQ, u16* phiKT, u16* vT, u16* qloc, u16* kloc, u16* vloc)
{
  extern __shared__ char smem[];
  char* A0 = smem;            // 16K (128 rows x 64 k)
  char* A1 = smem + 16384;    // 16K
  char* B0 = smem + 32768;    // 32K (256 rows x 64 k)
  char* B1 = smem + 65536;    // 32K

  const int t = threadIdx.x, lane = t & 63, w = t >> 6;
  const int wm = w >> 2, wn = w & 3;   // 2M x 4N waves; per-wave 64x64

  // XCD swizzle: 768 blocks = 96 contiguous per XCD, mt-fastest
  int bid = blockIdx.x;
  int swz = (bid & 7) * 96 + (bid >> 3);
  int mt = swz & 31, ntile = swz >> 5;      // 32 m-tiles x 24 n-tiles
  int m0 = mt << 7;                          // 128-row tile
  int n0g = ntile << 8;                      // 256-col tile
  int wi = n0g >> 10;
  int n0 = n0g & 1023;
  const u16* Bp = wi==0?wt0: wi==1?wt1: wi==2?wt2: wi==3?wt3: wi==4?wt4: wt5;
  const float* bsel = wi==0?b0: wi==1?b1: wi==2?b2: wi==3?b3: wi==4?b4: b5;

  // A tile: 128x64 = 2 gload16/thread; B tile: 256x64 = 4 gload16/thread.
  // LDS linear dest; source pre-swizzled: byte col ^= ((row&7)<<4).
  auto STAGE_A = [&](char* dst, int ktile){
    #pragma unroll
    for (int j = 0; j < 2; j++){
      int r = (w << 3) + (lane >> 3) + (j << 6);
      int csw = ((lane & 7) << 4) ^ ((r & 7) << 4);
      gload16((const char*)(h + (size_t)(m0 + r) * 1024 + ktile * 64) + csw,
              dst + (((w << 3) + (j << 6)) << 7));
    }
  };
  auto STAGE_B = [&](char* dst, int ktile){
    #pragma unroll
    for (int j = 0; j < 4; j++){
      int r = (w << 3) + (lane >> 3) + (j << 6);
      int csw = ((lane & 7) << 4) ^ ((r & 7) << 4);
      gload16((const char*)(Bp + (size_t)(n0 + r) * 1024 + ktile * 64) + csw,
              dst + (((w << 3) + (j << 6)) << 7));
    }
  };
  auto LDA = [&](const char* ab, int m, int kk) -> bf16x8 {
    int ra = (wm << 6) + (m << 4) + (lane & 15);          // 0..127
    return *(const bf16x8*)(ab + (ra << 7) + (((kk << 6) + ((lane >> 4) << 4)) ^ ((ra & 7) << 4)));
  };
  auto LDB = [&](const char* bb, int n, int kk) -> bf16x8 {
    int rb = (wn << 6) + (n << 4) + (lane & 15);          // 0..255
    return *(const bf16x8*)(bb + (rb << 7) + (((kk << 6) + ((lane >> 4) << 4)) ^ ((rb & 7) << 4)));
  };

  f32x4 acc[4][4];
  #pragma unroll
  for (int m = 0; m < 4; m++)
    #pragma unroll
    for (int n = 0; n < 4; n++) acc[m][n] = (f32x4){0.f,0.f,0.f,0.f};

  const int NT = 16;   // K=1024 / 64
  // prologue: A0<-t0 (2), B0<-t0 (4), A1<-t1 (2); drain A0,B0 (leave A1's 2 in flight)
  STAGE_A(A0, 0);
  STAGE_B(B0, 0);
  STAGE_A(A1, 1);
  VM2
  SBAR

  #pragma unroll 1
  for (int i = 0; i < NT/2; i++){
    int e = 2*i, o = e + 1;
    int tn0 = (e + 2 < NT) ? e + 2 : NT - 1;   // clamp keeps vmcnt counts exact
    int tn1 = (o + 2 < NT) ? o + 2 : NT - 1;
    bf16x8 af[4][2], bf01[2][2], bf23[2][2];

    // P1: stage B1<-o; read A0 all-m + B0 n0-1; bar; MFMA acc[*][0..1]
    STAGE_B(B1, o);
    #pragma unroll
    for (int m = 0; m < 4; m++){ af[m][0] = LDA(A0, m, 0); af[m][1] = LDA(A0, m, 1); }
    #pragma unroll
    for (int n = 0; n < 2; n++){ bf01[n][0] = LDB(B0, n, 0); bf01[n][1] = LDB(B0, n, 1); }
    SBAR LGKM0
    MFMA8x2(af, bf01, 0)

    // P2: read B0 n2-3; stage A0<-tn0; vmcnt(2) (drains prev A1 stage + P1's B1); bar; MFMA acc[*][2..3]
    #pragma unroll
    for (int n = 0; n < 2; n++){ bf23[n][0] = LDB(B0, n + 2, 0); bf23[n][1] = LDB(B0, n + 2, 1); }
    STAGE_A(A0, tn0);
    VM2
    SBAR LGKM0
    MFMA8x2(af, bf23, 2)

    // P3: stage B0<-tn0; read A1 all-m + B1 n0-1; bar; MFMA
    STAGE_B(B0, tn0);
    #pragma unroll
    for (int m = 0; m < 4; m++){ af[m][0] = LDA(A1, m, 0); af[m][1] = LDA(A1, m, 1); }
    #pragma unroll
    for (int n = 0; n < 2; n++){ bf01[n][0] = LDB(B1, n, 0); bf01[n][1] = LDB(B1, n, 1); }
    SBAR LGKM0
    MFMA8x2(af, bf01, 0)

    // P4: read B1 n2-3; stage A1<-tn1; vmcnt(2) (drains P2's A0 + P3's B0); bar; MFMA
    #pragma unroll
    for (int n = 0; n < 2; n++){ bf23[n][0] = LDB(B1, n + 2, 0); bf23[n][1] = LDB(B1, n + 2, 1); }
    STAGE_A(A1, tn1);
    VM2
    SBAR LGKM0
    MFMA8x2(af, bf23, 2)
  }
  VM0   // drain clamped tail stages before LDS teardown

  // epilogue
  #pragma unroll
  for (int n = 0; n < 4; n++){
    int col = n0 + (wn << 6) + (n << 4) + (lane & 15);
    float bv = bsel[col];
    #pragma unroll
    for (int m = 0; m < 4; m++){
      int r0 = m0 + (wm << 6) + (m << 4) + ((lane >> 4) << 2);
      float e[4];
      #pragma unroll
      for (int r = 0; r < 4; r++) e[r] = acc[m][n][r] + bv;
      if (wi == 0){
        #pragma unroll
        for (int r = 0; r < 4; r++) phiQ[(size_t)(r0 + r) * DM + col] = f2bf(phi_elu(e[r]));
      } else if (wi == 1 || wi == 2){
        union { u16 s[4]; ushort4 v; } o;
        #pragma unroll
        for (int r = 0; r < 4; r++) o.s[r] = f2bf(wi == 1 ? phi_elu(e[r]) : e[r]);
        int bb = r0 >> 11, sl = r0 & 2047;
        u16* dst = (wi == 1) ? phiKT : vT;
        *(ushort4*)(dst + ((size_t)(bb << 10) + col) * SEQ + sl) = o.v;
      } else {
        u16* dst = wi==3 ? qloc : wi==4 ? kloc : vloc;
        #pragma unroll
        for (int r = 0; r < 4; r++) dst[(size_t)(r0 + r) * DM + col] = f2bf(e[r]);
      }
    }
  }
}

// ---------------- 128x128 m97-style GEMM core (N=1024 GEMMs) ----------------
template<int NCHUNK>
__device__ __forceinline__ void gemm_core(const u16* A0, const u16* A1, const u16* A2, int lda,
                                          const u16* B, int ldb, int K, int m0, int n0,
                                          u16* ldsA, u16* ldsB, f32x4 (&acc)[4][4])
{
  const int t = threadIdx.x, lane = t & 63, w = t >> 6;
  const int wm = w >> 1, wn = w & 1;
  int srow[4], scol[4];
  #pragma unroll
  for (int j = 0; j < 4; j++){
    int r = ((w << 2) + j) * 8 + (lane >> 3);
    int csw = (lane & 7) << 4;
    srow[j] = r;
    scol[j] = csw ^ ((r & 7) << 4);
  }
  for (int k0 = 0; k0 < K; k0 += 64){
    const u16* Ab;
    if (NCHUNK == 3){
      int ci = k0 >> 10;
      const u16* cp = (ci == 0) ? A0 : ((ci == 1) ? A1 : A2);
      Ab = cp + (k0 & 1023);
    } else {
      Ab = A0 + k0;
    }
    const u16* Bb = B + k0;
    #pragma unroll
    for (int j = 0; j < 4; j++){
      gload16((const char*)(Ab + (size_t)(m0 + srow[j]) * lda) + scol[j],
              (char*)ldsA + (((w << 2) + j) << 10));
      gload16((const char*)(Bb + (size_t)(n0 + srow[j]) * ldb) + scol[j],
              (char*)ldsB + (((w << 2) + j) << 10));
    }
    __syncthreads();
    #pragma unroll
    for (int kk = 0; kk < 2; kk++){
      bf16x8 a[4], b[4];
      #pragma unroll
      for (int m = 0; m < 4; m++){
        int ra = wm*64 + m*16 + (lane & 15);
        int byt = ra*128 + (((kk << 6) + ((lane >> 4) << 4)) ^ ((ra & 7) << 4));
        a[m] = *(const bf16x8*)((const char*)ldsA + byt);
      }
      #pragma unroll
      for (int n = 0; n < 4; n++){
        int rb = wn*64 + n*16 + (lane & 15);
        int byt = rb*128 + (((kk << 6) + ((lane >> 4) << 4)) ^ ((rb & 7) << 4));
        b[n] = *(const bf16x8*)((const char*)ldsB + byt);
      }
      #pragma unroll
      for (int m = 0; m < 4; m++)
        #pragma unroll
        for (int n = 0; n < 4; n++)
          acc[m][n] = __builtin_amdgcn_mfma_f32_16x16x32_bf16(a[m], b[n], acc[m][n], 0, 0, 0);
    }
    __syncthreads();
  }
}

#define EPI_COORDS \
  const int lane = threadIdx.x & 63, w = threadIdx.x >> 6; \
  const int wm = w >> 1, wn = w & 1;

#define ZERO_ACC f32x4 acc[4][4]; \
  _Pragma("unroll") for (int m = 0; m < 4; m++) _Pragma("unroll") for (int n = 0; n < 4; n++) acc[m][n] = (f32x4){0.f,0.f,0.f,0.f};

// ---------------- kv^T = v^T . phiK^T  (per batch) ----------------
__global__ __launch_bounds__(256) void kkv(const u16* __restrict__ vT, const u16* __restrict__ phiKT,
                                           u16* __restrict__ kvT){
  __shared__ u16 ldsA[8192], ldsB[8192];
  int b = blockIdx.z;
  int m0 = blockIdx.x << 7, n0 = blockIdx.y << 7;
  const u16* A = vT + (size_t)b * DM * SEQ;
  const u16* B = phiKT + (size_t)b * DM * SEQ;
  ZERO_ACC
  gemm_core<1>(A, 0, 0, SEQ, B, SEQ, SEQ, m0, n0, ldsA, ldsB, acc);
  EPI_COORDS
  u16* C = kvT + (size_t)b * DM * DM;
  #pragma unroll
  for (int n = 0; n < 4; n++){
    int col = n0 + wn*64 + n*16 + (lane & 15);
    #pragma unroll
    for (int m = 0; m < 4; m++){
      int r0 = m0 + wm*64 + m*16 + ((lane >> 4) << 2);
      #pragma unroll
      for (int r = 0; r < 4; r++) C[(size_t)(r0 + r) * DM + col] = f2bf(acc[m][n][r]);
    }
  }
}

// ---------------- num = phiQ . kv^T, lin = num / (denom + 1e-6) ----------------
__global__ __launch_bounds__(256) void knum(const u16* __restrict__ phiQ, const u16* __restrict__ kvT,
                                            const float* __restrict__ dn, u16* __restrict__ lin){
  __shared__ u16 ldsA[8192], ldsB[8192];
  int b = blockIdx.z;
  int m0 = blockIdx.x << 7, n0 = blockIdx.y << 7;
  const u16* A = phiQ + (size_t)b * SEQ * DM;
  const u16* B = kvT + (size_t)b * DM * DM;
  ZERO_ACC
  gemm_core<1>(A, 0, 0, DM, B, DM, DM, m0, n0, ldsA, ldsB, acc);
  EPI_COORDS
  #pragma unroll
  for (int n = 0; n < 4; n++){
    int col = n0 + wn*64 + n*16 + (lane & 15);
    #pragma unroll
    for (int m = 0; m < 4; m++){
      int r0 = m0 + wm*64 + m*16 + ((lane >> 4) << 2);
      #pragma unroll
      for (int r = 0; r < 4; r++){
        float d = dn[(b << 11) + r0 + r] + 1e-6f;
        lin[((size_t)(b << 11) + r0 + r) * DM + col] = f2bf(acc[m][n][r] / d);
      }
    }
  }
}

// ---------------- ksum[b][d] = sum_s phiKT[b][d][s] ----------------
__global__ __launch_bounds__(256) void ksumk(const u16* __restrict__ kt, float* __restrict__ ks){
  int row = blockIdx.x, t = threadIdx.x;
  const ushort4* src = (const ushort4*)(kt + (size_t)row * SEQ);
  float s = 0.f;
  for (int i = t; i < 512; i += 256){
    ushort4 v = src[i];
    s += bf2f(v.x) + bf2f(v.y) + bf2f(v.z) + bf2f(v.w);
  }
  #pragma unroll
  for (int o = 1; o < 64; o <<= 1) s += __shfl_xor(s, o);
  __shared__ float red[4];
  if ((t & 63) == 0) red[t >> 6] = s;
  __syncthreads();
  if (t == 0) ks[row] = red[0] + red[1] + red[2] + red[3];
}

// ---------------- denom[row] = phiQ[row] . ksum[b] ----------------
__global__ __launch_bounds__(256) void kdenom(const u16* __restrict__ phiQ, const float* __restrict__ ks,
                                              float* __restrict__ dn){
  int row = blockIdx.x, t = threadIdx.x;
  ushort4 v = ((const ushort4*)(phiQ + (size_t)row * DM))[t];
  float4 kk = ((const float4*)(ks + ((size_t)(row >> 11) << 10)))[t];
  float s = bf2f(v.x)*kk.x + bf2f(v.y)*kk.y + bf2f(v.z)*kk.z + bf2f(v.w)*kk.w;
  #pragma unroll
  for (int o = 1; o < 64; o <<= 1) s += __shfl_xor(s, o);
  __shared__ float red[4];
  if ((t & 63) == 0) red[t >> 6] = s;
  __syncthreads();
  if (t == 0) dn[row] = red[0] + red[1] + red[2] + red[3];
}

// ---------------- sliding-window attention ----------------
__global__ __launch_bounds__(256) void kwin(const u16* __restrict__ qloc, const u16* __restrict__ kloc,
                                            const u16* __restrict__ vloc, const float* __restrict__ rel_bias,
                                            u16* __restrict__ wout)
{
  __shared__ float KV[128 * 68];
  __shared__ float Ssm[64 * 84];
  __shared__ float bias_s[65];
  int qt = blockIdx.x, hh = blockIdx.y, b = blockIdx.z;
  int q0 = qt << 6;
  int t = threadIdx.x;
  int q = t >> 2, sub = t & 3, qq = q & 15;
  size_t base = (size_t)b * SEQ * DM + hh * 64;
  for (int i = t; i < 1024; i += 256){
    int r = i >> 3, seg = i & 7;
    int p = q0 + r - 32;
    float* dst = &KV[r * 68 + (seg << 3)];
    if ((unsigned)p < SEQ){
      int4 raw = *(const int4*)(kloc + base + (size_t)p * DM + (seg << 3));
      const u16* s = (const u16*)&raw;
      #pragma unroll
      for (int j = 0; j < 8; j++) dst[j] = bf2f(s[j]);
    } else {
      #pragma unroll
      for (int j = 0; j < 8; j++) dst[j] = 0.f;
    }
  }
  if (t < 65) bias_s[t] = rel_bias[(t + 32) * 16 + hh];
  float qreg[16];
  {
    const u16* qp = qloc + base + (size_t)(q0 + q) * DM + (sub << 4);
    int4 raw0 = *(const int4*)qp;
    int4 raw1 = *(const int4*)(qp + 8);
    const u16* s0 = (const u16*)&raw0; const u16* s1 = (const u16*)&raw1;
    #pragma unroll
    for (int j = 0; j < 8; j++){ qreg[j] = bf2f(s0[j]); qreg[8 + j] = bf2f(s1[j]); }
  }
  __syncthreads();
  int rlo = (t >> 6) << 4;
  for (int rr = 0; rr < 80; rr++){
    int r = rlo + rr;
    const float* kr = &KV[r * 68 + (sub << 4)];
    float s = 0.f;
    #pragma unroll
    for (int i = 0; i < 16; i++) s += qreg[i] * kr[i];
    s += __shfl_xor(s, 1); s += __shfl_xor(s, 2);
    int wrel = r - q;
    int p = q0 + r - 32;
    float sc = -1e30f;
    if ((unsigned)wrel <= 64u && (unsigned)p < SEQ) sc = s * 0.125f + bias_s[wrel];
    if (sub == 0) Ssm[q * 84 + rr] = sc;
  }
  __syncthreads();
  for (int i = t; i < 1024; i += 256){
    int r = i >> 3, seg = i & 7;
    int p = q0 + r - 32;
    float* dst = &KV[r * 68 + (seg << 3)];
    if ((unsigned)p < SEQ){
      int4 raw = *(const int4*)(vloc + base + (size_t)p * DM + (seg << 3));
      const u16* s = (const u16*)&raw;
      #pragma unroll
      for (int j = 0; j < 8; j++) dst[j] = bf2f(s[j]);
    } else {
      #pragma unroll
      for (int j = 0; j < 8; j++) dst[j] = 0.f;
    }
  }
  float mloc = -1e30f;
  for (int wrel = sub; wrel <= 64; wrel += 4) mloc = fmaxf(mloc, Ssm[q * 84 + qq + wrel]);
  mloc = fmaxf(mloc, __shfl_xor(mloc, 1));
  mloc = fmaxf(mloc, __shfl_xor(mloc, 2));
  float lloc = 0.f;
  for (int wrel = sub; wrel <= 64; wrel += 4) lloc += __expf(Ssm[q * 84 + qq + wrel] - mloc);
  lloc += __shfl_xor(lloc, 1); lloc += __shfl_xor(lloc, 2);
  float inv = 1.0f / lloc;
  for (int wrel = sub; wrel <= 64; wrel += 4)
    Ssm[q * 84 + qq + wrel] = __expf(Ssm[q * 84 + qq + wrel] - mloc) * inv;
  __syncthreads();
  float accv[16];
  #pragma unroll
  for (int i = 0; i < 16; i++) accv[i] = 0.f;
  for (int rr = 0; rr < 80; rr++){
    int r = rlo + rr;
    float pv = Ssm[q * 84 + rr];
    pv = ((unsigned)(r - q) <= 64u) ? pv : 0.f;
    const float* vr = &KV[r * 68 + (sub << 4)];
    #pragma unroll
    for (int i = 0; i < 16; i++) accv[i] += pv * vr[i];
  }
  union { u16 s[16]; int4 v[2]; } ob;
  #pragma unroll
  for (int i = 0; i < 16; i++) ob.s[i] = f2bf(accv[i]);
  u16* dst = wout + base + (size_t)(q0 + q) * DM + (sub << 4);
  *(int4*)dst = ob.v[0];
  *(int4*)(dst + 8) = ob.v[1];
}

// ---------------- gate GEMM 1: relu([lin,win,h] . wg1 + bg1) ----------------
__global__ __launch_bounds__(256) void kgate1(const u16* __restrict__ lin, const u16* __restrict__ win,
                                              const u16* __restrict__ h, const u16* __restrict__ wg1T,
                                              const float* __restrict__ bg1, u16* __restrict__ g1){
  __shared__ u16 ldsA[8192], ldsB[8192];
  int m0 = blockIdx.x << 7, n0 = blockIdx.y << 7;
  ZERO_ACC
  gemm_core<3>(lin, win, h, DM, wg1T, 3072, 3072, m0, n0, ldsA, ldsB, acc);
  EPI_COORDS
  #pragma unroll
  for (int n = 0; n < 4; n++){
    int col = n0 + wn*64 + n*16 + (lane & 15);
    float bv = bg1[col];
    #pragma unroll
    for (int m = 0; m < 4; m++){
      int r0 = m0 + wm*64 + m*16 + ((lane >> 4) << 2);
      #pragma unroll
      for (int r = 0; r < 4; r++){
        float v = acc[m][n][r] + bv;
        g1[(size_t)(r0 + r) * DM + col] = f2bf(v > 0.f ? v : 0.f);
      }
    }
  }
}

// ---------------- gate GEMM 2 + sigmoid + convex combine ----------------
__global__ __launch_bounds__(256) void kgate2(const u16* __restrict__ g1, const u16* __restrict__ wg2T,
                                              const float* __restrict__ bg2, const u16* __restrict__ lin,
                                              const u16* __restrict__ win, u16* __restrict__ outc){
  __shared__ u16 ldsA[8192], ldsB[8192];
  int m0 = blockIdx.x << 7, n0 = blockIdx.y << 7;
  ZERO_ACC
  gemm_core<1>(g1, 0, 0, DM, wg2T, DM, DM, m0, n0, ldsA, ldsB, acc);
  EPI_COORDS
  #pragma unroll
  for (int n = 0; n < 4; n++){
    int col = n0 + wn*64 + n*16 + (lane & 15);
    float bv = bg2[col];
    #pragma unroll
    for (int m = 0; m < 4; m++){
      int r0 = m0 + wm*64 + m*16 + ((lane >> 4) << 2);
      #pragma unroll
      for (int r = 0; r < 4; r++){
        size_t idx = (size_t)(r0 + r) * DM + col;
        float g = 1.0f / (1.0f + __expf(-(acc[m][n][r] + bv)));
        float lv = bf2f(lin[idx]), wv = bf2f(win[idx]);
        outc[idx] = f2bf(g * lv + (1.0f - g) * wv);
      }
    }
  }
}

// ---------------- final GEMM: outc . wo + bo + x -> fp32 out ----------------
__global__ __launch_bounds__(256) void kfinal(const u16* __restrict__ outc, const u16* __restrict__ woT,
                                              const float* __restrict__ bo, const float* __restrict__ x,
                                              float* __restrict__ out){
  __shared__ u16 ldsA[8192], ldsB[8192];
  int m0 = blockIdx.x << 7, n0 = blockIdx.y << 7;
  ZERO_ACC
  gemm_core<1>(outc, 0, 0, DM, woT, DM, DM, m0, n0, ldsA, ldsB, acc);
  EPI_COORDS
  #pragma unroll
  for (int n = 0; n < 4; n++){
    int col = n0 + wn*64 + n*16 + (lane & 15);
    float bv = bo[col];
    #pragma unroll
    for (int m = 0; m < 4; m++){
      int r0 = m0 + wm*64 + m*16 + ((lane >> 4) << 2);
      #pragma unroll
      for (int r = 0; r < 4; r++){
        size_t idx = (size_t)(r0 + r) * DM + col;
        out[idx] = acc[m][n][r] + bv + x[idx];
      }
    }
  }
}

extern "C" void kernel_launch(void* const* d_in, const int* in_sizes, int n_in,
                              void* d_out, int out_size, void* d_ws, size_t ws_size,
                              hipStream_t stream)
{
  const float* x      = (const float*)d_in[0];
  const float* wq_lin = (const float*)d_in[1];  const float* bq_lin = (const float*)d_in[2];
  const float* wk_lin = (const float*)d_in[3];  const float* bk_lin = (const float*)d_in[4];
  const float* wv_lin = (const float*)d_in[5];  const float* bv_lin = (const float*)d_in[6];
  const float* wq_loc = (const float*)d_in[7];  const float* bq_loc = (const float*)d_in[8];
  const float* wk_loc = (const float*)d_in[9];  const float* bk_loc = (const float*)d_in[10];
  const float* wv_loc = (const float*)d_in[11]; const float* bv_loc = (const float*)d_in[12];
  const float* wo     = (const float*)d_in[13]; const float* bo     = (const float*)d_in[14];
  const float* wg1    = (const float*)d_in[15]; const float* bg1    = (const float*)d_in[16];
  const float* wg2    = (const float*)d_in[17]; const float* bg2    = (const float*)d_in[18];
  const float* rel_bias = (const float*)d_in[19];
  const float* ln_g   = (const float*)d_in[20]; const float* ln_b   = (const float*)d_in[21];

  char* ws = (char*)d_ws;
  size_t off = 0;
  auto alloc = [&](size_t bytes) -> void* {
    void* p = ws + off;
    off += (bytes + 255) & ~(size_t)255;
    return p;
  };
  const size_t MB2 = (size_t)1024 * 1024 * 2;
  const size_t ACT = (size_t)4096 * 1024 * 2;
  u16* wT[6]; for (int i = 0; i < 6; i++) wT[i] = (u16*)alloc(MB2);
  u16* woT   = (u16*)alloc(MB2);
  u16* wg1T  = (u16*)alloc((size_t)1024 * 3072 * 2);
  u16* wg2T  = (u16*)alloc(MB2);
  u16* hbf   = (u16*)alloc(ACT);
  u16* phiQ  = (u16*)alloc(ACT);
  u16* phiKT = (u16*)alloc(ACT);
  u16* vT    = (u16*)alloc(ACT);
  u16* qloc  = (u16*)alloc(ACT);
  u16* kloc  = (u16*)alloc(ACT);
  u16* vloc  = (u16*)alloc(ACT);
  u16* kvT   = (u16*)alloc(2 * MB2);
  float* ksum = (float*)alloc(2 * 1024 * 4);
  float* dnm  = (float*)alloc(4096 * 4);
  u16* lin   = (u16*)alloc(ACT);
  u16* win   = (u16*)alloc(ACT);
  u16* g1    = phiQ;   // reuse: phiQ dead after knum
  u16* outc  = vT;     // reuse: vT dead after kkv

  hipFuncSetAttribute((const void*)kqkv8, hipFuncAttributeMaxDynamicSharedMemorySize, 98304);

  dim3 blk(256);
  TP tp;
  tp.src[0]=wq_lin; tp.src[1]=wk_lin; tp.src[2]=wv_lin; tp.src[3]=wq_loc; tp.src[4]=wk_loc;
  tp.src[5]=wv_loc; tp.src[6]=wo; tp.src[7]=wg1; tp.src[8]=wg2;
  tp.dst[0]=wT[0]; tp.dst[1]=wT[1]; tp.dst[2]=wT[2]; tp.dst[3]=wT[3]; tp.dst[4]=wT[4];
  tp.dst[5]=wT[5]; tp.dst[6]=woT; tp.dst[7]=wg1T; tp.dst[8]=wg2T;
  for (int i = 0; i < 9; i++) tp.K[i] = (i == 7) ? 3072 : 1024;
  ktransall<<<dim3(16,48,9), blk, 0, stream>>>(tp);

  kln<<<4096, blk, 0, stream>>>(x, ln_g, ln_b, hbf);

  kqkv8<<<768, 512, 98304, stream>>>(hbf, wT[0], wT[1], wT[2], wT[3], wT[4], wT[5],
                                     bq_lin, bk_lin, bv_lin, bq_loc, bk_loc, bv_loc,
                                     phiQ, phiKT, vT, qloc, kloc, vloc);

  ksumk<<<2048, blk, 0, stream>>>(phiKT, ksum);
  kdenom<<<4096, blk, 0, stream>>>(phiQ, ksum, dnm);
  kkv<<<dim3(8,8,2), blk, 0, stream>>>(vT, phiKT, kvT);
  knum<<<dim3(16,8,2), blk, 0, stream>>>(phiQ, kvT, dnm, lin);

  kwin<<<dim3(32,16,2), blk, 0, stream>>>(qloc, kloc, vloc, rel_bias, win);

  kgate1<<<dim3(32,8), blk, 0, stream>>>(lin, win, hbf, wg1T, bg1, g1);
  kgate2<<<dim3(32,8), blk, 0, stream>>>(g1, wg2T, bg2, lin, win, outc);
  kfinal<<<dim3(32,8), blk, 0, stream>>>(outc, woT, bo, x, (float*)d_out);
}

// Round 4
// 264.354 us; speedup vs baseline: 1.2564x; 1.1960x over previous
//
#include <hip/hip_runtime.h>

typedef unsigned short u16;
typedef unsigned int u32;
typedef float f32x4 __attribute__((ext_vector_type(4)));
typedef __bf16 bf16x8 __attribute__((ext_vector_type(8)));

#define SEQ 2048
#define DM 1024

__device__ __forceinline__ float bf2f(u16 a){
  u32 b = ((u32)a) << 16; float f; __builtin_memcpy(&f, &b, 4); return f;
}
__device__ __forceinline__ u16 f2bf(float f){
  u32 b; __builtin_memcpy(&b, &f, 4);
  b += 0x7fffu + ((b >> 16) & 1u);
  return (u16)(b >> 16);
}

__device__ __forceinline__ void gload16(const void* g, void* l){
  __builtin_amdgcn_global_load_lds((const __attribute__((address_space(1))) u32*)g,
                                   (__attribute__((address_space(3))) u32*)l, 16, 0, 0);
}

#define SBAR  __builtin_amdgcn_sched_barrier(0); __builtin_amdgcn_s_barrier(); __builtin_amdgcn_sched_barrier(0);
#define VM0   asm volatile("s_waitcnt vmcnt(0)" ::: "memory"); __builtin_amdgcn_sched_barrier(0);
#define VM6   asm volatile("s_waitcnt vmcnt(6)" ::: "memory"); __builtin_amdgcn_sched_barrier(0);
#define VM8   asm volatile("s_waitcnt vmcnt(8)" ::: "memory"); __builtin_amdgcn_sched_barrier(0);

// 16 MFMA consuming a 4-frag A set and 4-frag B set (one kk half of a 64x64 wave tile)
#define MFMA16(AF, BF) \
  __builtin_amdgcn_s_setprio(1); \
  _Pragma("unroll") for (int m_ = 0; m_ < 4; m_++) \
  _Pragma("unroll") for (int n_ = 0; n_ < 4; n_++) \
    acc[m_][n_] = __builtin_amdgcn_mfma_f32_16x16x32_bf16(AF[m_], BF[n_], acc[m_][n_], 0,0,0); \
  __builtin_amdgcn_s_setprio(0);

// ---------------- fused weight convert+transpose: 9 matrices, one launch ----------------
struct TP { const float* src[9]; u16* dst[9]; int K[9]; };

__global__ __launch_bounds__(256) void ktransall(TP tp){
  __shared__ float tile[64][65];
  int z = blockIdx.z;
  int K = tp.K[z];
  int kb = blockIdx.y << 6, nb = blockIdx.x << 6;
  if (kb >= K) return;
  const float* W = tp.src[z];
  u16* WT = tp.dst[z];
  const int N = 1024;
  int t = threadIdx.x;
  #pragma unroll
  for (int i = 0; i < 4; i++){
    int idx = t + (i << 8);
    int r = idx >> 4, c = (idx & 15) << 2;
    float4 v = *(const float4*)(W + (size_t)(kb + r) * N + nb + c);
    tile[r][c] = v.x; tile[r][c+1] = v.y; tile[r][c+2] = v.z; tile[r][c+3] = v.w;
  }
  __syncthreads();
  #pragma unroll
  for (int i = 0; i < 2; i++){
    int idx = t + (i << 8);
    int n = idx >> 3, k8 = (idx & 7) << 3;
    union { u16 s[8]; int4 v; } u;
    #pragma unroll
    for (int j = 0; j < 8; j++) u.s[j] = f2bf(tile[k8 + j][n]);
    *(int4*)(WT + (size_t)(nb + n) * K + kb + k8) = u.v;
  }
}

// ---------------- layernorm: x f32 -> h bf16 ----------------
__global__ __launch_bounds__(256) void kln(const float* __restrict__ x, const float* __restrict__ gg,
                                           const float* __restrict__ bb, u16* __restrict__ h){
  int row = blockIdx.x, t = threadIdx.x;
  float4 xv = ((const float4*)(x + (size_t)row * DM))[t];
  float s  = xv.x + xv.y + xv.z + xv.w;
  float s2 = xv.x*xv.x + xv.y*xv.y + xv.z*xv.z + xv.w*xv.w;
  #pragma unroll
  for (int o = 1; o < 64; o <<= 1){ s += __shfl_xor(s, o); s2 += __shfl_xor(s2, o); }
  __shared__ float r1[4], r2[4];
  if ((t & 63) == 0){ r1[t >> 6] = s; r2[t >> 6] = s2; }
  __syncthreads();
  float S = r1[0]+r1[1]+r1[2]+r1[3], S2 = r2[0]+r2[1]+r2[2]+r2[3];
  float mu = S * (1.0f/DM);
  float var = S2 * (1.0f/DM) - mu*mu;
  float rstd = rsqrtf(var + 1e-5f);
  float4 gv = ((const float4*)gg)[t], bv = ((const float4*)bb)[t];
  ushort4 o;
  o.x = f2bf((xv.x - mu)*rstd*gv.x + bv.x);
  o.y = f2bf((xv.y - mu)*rstd*gv.y + bv.y);
  o.z = f2bf((xv.z - mu)*rstd*gv.z + bv.z);
  o.w = f2bf((xv.w - mu)*rstd*gv.w + bv.w);
  ((ushort4*)(h + (size_t)row * DM))[t] = o;
}

__device__ __forceinline__ float phi_elu(float v){ return v > 0.f ? v + 1.f : __expf(v); }

// ================= kqkv8: 128x256-tile, 8 waves, register-prefetch pipeline =================
// Phases split by kk-half. During phase (t,kk): prefetch reads for the next phase,
// barrier, stage DMA two K-tiles ahead (A:2 + B:4 issues), MFMA on prefetched frags.
// Counted vmcnt(6) keeps the next tile's 6 stages in flight. Never vmcnt(0) in-loop.
__global__ __launch_bounds__(512, 2) void kqkv8(
  const u16* __restrict__ h,
  const u16* wt0, const u16* wt1, const u16* wt2, const u16* wt3, const u16* wt4, const u16* wt5,
  const float* b0, const float* b1, const float* b2, const float* b3, const float* b4, const float* b5,
  u16* phiQ, u16* phiKT, u16* vT, u16* qloc, u16* kloc, u16* vloc)
{
  extern __shared__ char smem[];
  char* LA0 = smem;            // 16K (128 x 64)
  char* LA1 = smem + 16384;    // 16K
  char* LB0 = smem + 32768;    // 32K (256 x 64)
  char* LB1 = smem + 65536;    // 32K -> 96K total

  const int t = threadIdx.x, lane = t & 63, w = t >> 6;
  const int wm = w >> 2, wn = w & 3;   // 2M x 4N waves; per-wave 64x64

  int bid = blockIdx.x;
  int swz = (bid & 7) * 96 + (bid >> 3);
  int mt = swz & 31, ntile = swz >> 5;
  int m0 = mt << 7;
  int n0g = ntile << 8;
  int wi = n0g >> 10;
  int n0 = n0g & 1023;
  const u16* Bp = wi==0?wt0: wi==1?wt1: wi==2?wt2: wi==3?wt3: wi==4?wt4: wt5;
  const float* bsel = wi==0?b0: wi==1?b1: wi==2?b2: wi==3?b3: wi==4?b4: b5;

  auto stageA = [&](char* dst, int kt){
    #pragma unroll
    for (int j = 0; j < 2; j++){
      int slot = (j << 9) + t;
      int r = slot >> 3;
      int csw = ((slot & 7) << 4) ^ ((r & 7) << 4);
      gload16((const char*)(h + (size_t)(m0 + r) * 1024 + (kt << 6)) + csw,
              dst + (((j << 9) + (w << 6)) << 4));
    }
  };
  auto stageB = [&](char* dst, int kt){
    #pragma unroll
    for (int j = 0; j < 4; j++){
      int slot = (j << 9) + t;
      int r = slot >> 3;
      int csw = ((slot & 7) << 4) ^ ((r & 7) << 4);
      gload16((const char*)(Bp + (size_t)(n0 + r) * 1024 + (kt << 6)) + csw,
              dst + (((j << 9) + (w << 6)) << 4));
    }
  };
  auto rdA = [&](const char* ab, int m, int kk) -> bf16x8 {
    int ra = (wm << 6) + (m << 4) + (lane & 15);
    return *(const bf16x8*)(ab + (ra << 7) + (((kk << 6) + ((lane >> 4) << 4)) ^ ((ra & 7) << 4)));
  };
  auto rdB = [&](const char* bb, int n, int kk) -> bf16x8 {
    int rb = (wn << 6) + (n << 4) + (lane & 15);
    return *(const bf16x8*)(bb + (rb << 7) + (((kk << 6) + ((lane >> 4) << 4)) ^ ((rb & 7) << 4)));
  };

  f32x4 acc[4][4];
  #pragma unroll
  for (int m = 0; m < 4; m++)
    #pragma unroll
    for (int n = 0; n < 4; n++) acc[m][n] = (f32x4){0.f,0.f,0.f,0.f};

  const int NT = 16;
  bf16x8 a0[4], bq0[4], a1[4], bq1[4];

  stageA(LA0, 0); stageB(LB0, 0);
  stageA(LA1, 1); stageB(LB1, 1);
  VM6 SBAR
  #pragma unroll
  for (int m = 0; m < 4; m++) a0[m] = rdA(LA0, m, 0);
  #pragma unroll
  for (int n = 0; n < 4; n++) bq0[n] = rdB(LB0, n, 0);

  #pragma unroll 1
  for (int i = 0; i < NT/2; i++){
    int e = 2*i, o = e + 1;
    int se = (e + 2 < NT) ? e + 2 : NT - 1;
    int so = (o + 2 < NT) ? o + 2 : NT - 1;
    // ph(e,0): prefetch (e,1); bar; stage tile e+2; MFMA on (e,0)
    #pragma unroll
    for (int m = 0; m < 4; m++) a1[m] = rdA(LA0, m, 1);
    #pragma unroll
    for (int n = 0; n < 4; n++) bq1[n] = rdB(LB0, n, 1);
    SBAR
    stageA(LA0, se); stageB(LB0, se);
    MFMA16(a0, bq0)
    // ph(e,1): wait tile o landed; bar; prefetch (o,0); MFMA on (e,1)
    VM6 SBAR
    #pragma unroll
    for (int m = 0; m < 4; m++) a0[m] = rdA(LA1, m, 0);
    #pragma unroll
    for (int n = 0; n < 4; n++) bq0[n] = rdB(LB1, n, 0);
    MFMA16(a1, bq1)
    // ph(o,0): prefetch (o,1); bar; stage tile o+2; MFMA on (o,0)
    #pragma unroll
    for (int m = 0; m < 4; m++) a1[m] = rdA(LA1, m, 1);
    #pragma unroll
    for (int n = 0; n < 4; n++) bq1[n] = rdB(LB1, n, 1);
    SBAR
    stageA(LA1, so); stageB(LB1, so);
    MFMA16(a0, bq0)
    // ph(o,1): wait tile e+2 landed; bar; prefetch next (e',0); MFMA on (o,1)
    VM6 SBAR
    if (i < NT/2 - 1){
      #pragma unroll
      for (int m = 0; m < 4; m++) a0[m] = rdA(LA0, m, 0);
      #pragma unroll
      for (int n = 0; n < 4; n++) bq0[n] = rdB(LB0, n, 0);
    }
    MFMA16(a1, bq1)
  }
  VM0

  // epilogue
  #pragma unroll
  for (int n = 0; n < 4; n++){
    int col = n0 + (wn << 6) + (n << 4) + (lane & 15);
    float bv = bsel[col];
    #pragma unroll
    for (int m = 0; m < 4; m++){
      int r0 = m0 + (wm << 6) + (m << 4) + ((lane >> 4) << 2);
      float e[4];
      #pragma unroll
      for (int r = 0; r < 4; r++) e[r] = acc[m][n][r] + bv;
      if (wi == 0){
        #pragma unroll
        for (int r = 0; r < 4; r++) phiQ[(size_t)(r0 + r) * DM + col] = f2bf(phi_elu(e[r]));
      } else if (wi == 1 || wi == 2){
        union { u16 s[4]; ushort4 v; } o;
        #pragma unroll
        for (int r = 0; r < 4; r++) o.s[r] = f2bf(wi == 1 ? phi_elu(e[r]) : e[r]);
        int bb = r0 >> 11, sl = r0 & 2047;
        u16* dst = (wi == 1) ? phiKT : vT;
        *(ushort4*)(dst + ((size_t)(bb << 10) + col) * SEQ + sl) = o.v;
      } else {
        u16* dst = wi==3 ? qloc : wi==4 ? kloc : vloc;
        #pragma unroll
        for (int r = 0; r < 4; r++) dst[(size_t)(r0 + r) * DM + col] = f2bf(e[r]);
      }
    }
  }
}

// ================= pipe128: 128x128-tile, 4 waves, register-prefetch pipeline =================
// Same schedule as kqkv8 but A,B both 16KB halves (4+4 stage issues -> vmcnt(8) steady).
template<int NCHUNK>
__device__ __forceinline__ void pipe128(const u16* A0c, const u16* A1c, const u16* A2c, int lda,
                                        const u16* B, int ldb, int K, int m0, int n0,
                                        char* LA0, char* LA1, char* LB0, char* LB1,
                                        f32x4 (&acc)[4][4])
{
  const int t = threadIdx.x, lane = t & 63, w = t >> 6;
  const int wm = w >> 1, wn = w & 1;
  const int NT = K >> 6;

  auto stageA = [&](char* dst, int kt){
    const u16* Ab;
    if (NCHUNK == 3){
      int ci = kt >> 4;
      const u16* cp = (ci == 0) ? A0c : ((ci == 1) ? A1c : A2c);
      Ab = cp + ((kt & 15) << 6);
    } else {
      Ab = A0c + (kt << 6);
    }
    #pragma unroll
    for (int j = 0; j < 4; j++){
      int slot = (j << 8) + t;
      int r = slot >> 3;
      int csw = ((slot & 7) << 4) ^ ((r & 7) << 4);
      gload16((const char*)(Ab + (size_t)(m0 + r) * lda) + csw,
              dst + (((j << 8) + (w << 6)) << 4));
    }
  };
  auto stageB = [&](char* dst, int kt){
    const u16* Bb = B + (kt << 6);
    #pragma unroll
    for (int j = 0; j < 4; j++){
      int slot = (j << 8) + t;
      int r = slot >> 3;
      int csw = ((slot & 7) << 4) ^ ((r & 7) << 4);
      gload16((const char*)(Bb + (size_t)(n0 + r) * ldb) + csw,
              dst + (((j << 8) + (w << 6)) << 4));
    }
  };
  auto rdA = [&](const char* ab, int m, int kk) -> bf16x8 {
    int ra = (wm << 6) + (m << 4) + (lane & 15);
    return *(const bf16x8*)(ab + (ra << 7) + (((kk << 6) + ((lane >> 4) << 4)) ^ ((ra & 7) << 4)));
  };
  auto rdB = [&](const char* bb, int n, int kk) -> bf16x8 {
    int rb = (wn << 6) + (n << 4) + (lane & 15);
    return *(const bf16x8*)(bb + (rb << 7) + (((kk << 6) + ((lane >> 4) << 4)) ^ ((rb & 7) << 4)));
  };

  bf16x8 a0[4], bq0[4], a1[4], bq1[4];

  stageA(LA0, 0); stageB(LB0, 0);
  stageA(LA1, 1); stageB(LB1, 1);
  VM8 SBAR
  #pragma unroll
  for (int m = 0; m < 4; m++) a0[m] = rdA(LA0, m, 0);
  #pragma unroll
  for (int n = 0; n < 4; n++) bq0[n] = rdB(LB0, n, 0);

  #pragma unroll 1
  for (int i = 0; i < NT/2; i++){
    int e = 2*i, o = e + 1;
    int se = (e + 2 < NT) ? e + 2 : NT - 1;
    int so = (o + 2 < NT) ? o + 2 : NT - 1;
    #pragma unroll
    for (int m = 0; m < 4; m++) a1[m] = rdA(LA0, m, 1);
    #pragma unroll
    for (int n = 0; n < 4; n++) bq1[n] = rdB(LB0, n, 1);
    SBAR
    stageA(LA0, se); stageB(LB0, se);
    MFMA16(a0, bq0)
    VM8 SBAR
    #pragma unroll
    for (int m = 0; m < 4; m++) a0[m] = rdA(LA1, m, 0);
    #pragma unroll
    for (int n = 0; n < 4; n++) bq0[n] = rdB(LB1, n, 0);
    MFMA16(a1, bq1)
    #pragma unroll
    for (int m = 0; m < 4; m++) a1[m] = rdA(LA1, m, 1);
    #pragma unroll
    for (int n = 0; n < 4; n++) bq1[n] = rdB(LB1, n, 1);
    SBAR
    stageA(LA1, so); stageB(LB1, so);
    MFMA16(a0, bq0)
    VM8 SBAR
    if (i < NT/2 - 1){
      #pragma unroll
      for (int m = 0; m < 4; m++) a0[m] = rdA(LA0, m, 0);
      #pragma unroll
      for (int n = 0; n < 4; n++) bq0[n] = rdB(LB0, n, 0);
    }
    MFMA16(a1, bq1)
  }
  VM0
}

#define PIPE_LDS \
  __shared__ char LA0[16384], LA1[16384], LB0[16384], LB1[16384];

#define EPI_COORDS \
  const int lane = threadIdx.x & 63, w = threadIdx.x >> 6; \
  const int wm = w >> 1, wn = w & 1;

#define ZERO_ACC f32x4 acc[4][4]; \
  _Pragma("unroll") for (int m = 0; m < 4; m++) _Pragma("unroll") for (int n = 0; n < 4; n++) acc[m][n] = (f32x4){0.f,0.f,0.f,0.f};

// ---------------- kv^T = v^T . phiK^T  (per batch) ----------------
__global__ __launch_bounds__(256) void kkv(const u16* __restrict__ vT, const u16* __restrict__ phiKT,
                                           u16* __restrict__ kvT){
  PIPE_LDS
  int b = blockIdx.z;
  int m0 = blockIdx.x << 7, n0 = blockIdx.y << 7;
  const u16* A = vT + (size_t)b * DM * SEQ;
  const u16* B = phiKT + (size_t)b * DM * SEQ;
  ZERO_ACC
  pipe128<1>(A, 0, 0, SEQ, B, SEQ, SEQ, m0, n0, LA0, LA1, LB0, LB1, acc);
  EPI_COORDS
  u16* C = kvT + (size_t)b * DM * DM;
  #pragma unroll
  for (int n = 0; n < 4; n++){
    int col = n0 + wn*64 + n*16 + (lane & 15);
    #pragma unroll
    for (int m = 0; m < 4; m++){
      int r0 = m0 + wm*64 + m*16 + ((lane >> 4) << 2);
      #pragma unroll
      for (int r = 0; r < 4; r++) C[(size_t)(r0 + r) * DM + col] = f2bf(acc[m][n][r]);
    }
  }
}

// ---------------- num = phiQ . kv^T, lin = num / (denom + 1e-6) ----------------
__global__ __launch_bounds__(256) void knum(const u16* __restrict__ phiQ, const u16* __restrict__ kvT,
                                            const float* __restrict__ dn, u16* __restrict__ lin){
  PIPE_LDS
  int b = blockIdx.z;
  int m0 = blockIdx.x << 7, n0 = blockIdx.y << 7;
  const u16* A = phiQ + (size_t)b * SEQ * DM;
  const u16* B = kvT + (size_t)b * DM * DM;
  ZERO_ACC
  pipe128<1>(A, 0, 0, DM, B, DM, DM, m0, n0, LA0, LA1, LB0, LB1, acc);
  EPI_COORDS
  #pragma unroll
  for (int n = 0; n < 4; n++){
    int col = n0 + wn*64 + n*16 + (lane & 15);
    #pragma unroll
    for (int m = 0; m < 4; m++){
      int r0 = m0 + wm*64 + m*16 + ((lane >> 4) << 2);
      #pragma unroll
      for (int r = 0; r < 4; r++){
        float d = dn[(b << 11) + r0 + r] + 1e-6f;
        lin[((size_t)(b << 11) + r0 + r) * DM + col] = f2bf(acc[m][n][r] / d);
      }
    }
  }
}

// ---------------- ksum[b][d] = sum_s phiKT[b][d][s] ----------------
__global__ __launch_bounds__(256) void ksumk(const u16* __restrict__ kt, float* __restrict__ ks){
  int row = blockIdx.x, t = threadIdx.x;
  const ushort4* src = (const ushort4*)(kt + (size_t)row * SEQ);
  float s = 0.f;
  for (int i = t; i < 512; i += 256){
    ushort4 v = src[i];
    s += bf2f(v.x) + bf2f(v.y) + bf2f(v.z) + bf2f(v.w);
  }
  #pragma unroll
  for (int o = 1; o < 64; o <<= 1) s += __shfl_xor(s, o);
  __shared__ float red[4];
  if ((t & 63) == 0) red[t >> 6] = s;
  __syncthreads();
  if (t == 0) ks[row] = red[0] + red[1] + red[2] + red[3];
}

// ---------------- denom[row] = phiQ[row] . ksum[b] ----------------
__global__ __launch_bounds__(256) void kdenom(const u16* __restrict__ phiQ, const float* __restrict__ ks,
                                              float* __restrict__ dn){
  int row = blockIdx.x, t = threadIdx.x;
  ushort4 v = ((const ushort4*)(phiQ + (size_t)row * DM))[t];
  float4 kk = ((const float4*)(ks + ((size_t)(row >> 11) << 10)))[t];
  float s = bf2f(v.x)*kk.x + bf2f(v.y)*kk.y + bf2f(v.z)*kk.z + bf2f(v.w)*kk.w;
  #pragma unroll
  for (int o = 1; o < 64; o <<= 1) s += __shfl_xor(s, o);
  __shared__ float red[4];
  if ((t & 63) == 0) red[t >> 6] = s;
  __syncthreads();
  if (t == 0) dn[row] = red[0] + red[1] + red[2] + red[3];
}

// ---------------- sliding-window attention ----------------
__global__ __launch_bounds__(256) void kwin(const u16* __restrict__ qloc, const u16* __restrict__ kloc,
                                            const u16* __restrict__ vloc, const float* __restrict__ rel_bias,
                                            u16* __restrict__ wout)
{
  __shared__ float KV[128 * 68];
  __shared__ float Ssm[64 * 84];
  __shared__ float bias_s[65];
  int qt = blockIdx.x, hh = blockIdx.y, b = blockIdx.z;
  int q0 = qt << 6;
  int t = threadIdx.x;
  int q = t >> 2, sub = t & 3, qq = q & 15;
  size_t base = (size_t)b * SEQ * DM + hh * 64;
  for (int i = t; i < 1024; i += 256){
    int r = i >> 3, seg = i & 7;
    int p = q0 + r - 32;
    float* dst = &KV[r * 68 + (seg << 3)];
    if ((unsigned)p < SEQ){
      int4 raw = *(const int4*)(kloc + base + (size_t)p * DM + (seg << 3));
      const u16* s = (const u16*)&raw;
      #pragma unroll
      for (int j = 0; j < 8; j++) dst[j] = bf2f(s[j]);
    } else {
      #pragma unroll
      for (int j = 0; j < 8; j++) dst[j] = 0.f;
    }
  }
  if (t < 65) bias_s[t] = rel_bias[(t + 32) * 16 + hh];
  float qreg[16];
  {
    const u16* qp = qloc + base + (size_t)(q0 + q) * DM + (sub << 4);
    int4 raw0 = *(const int4*)qp;
    int4 raw1 = *(const int4*)(qp + 8);
    const u16* s0 = (const u16*)&raw0; const u16* s1 = (const u16*)&raw1;
    #pragma unroll
    for (int j = 0; j < 8; j++){ qreg[j] = bf2f(s0[j]); qreg[8 + j] = bf2f(s1[j]); }
  }
  __syncthreads();
  int rlo = (t >> 6) << 4;
  for (int rr = 0; rr < 80; rr++){
    int r = rlo + rr;
    const float* kr = &KV[r * 68 + (sub << 4)];
    float s = 0.f;
    #pragma unroll
    for (int i = 0; i < 16; i++) s += qreg[i] * kr[i];
    s += __shfl_xor(s, 1); s += __shfl_xor(s, 2);
    int wrel = r - q;
    int p = q0 + r - 32;
    float sc = -1e30f;
    if ((unsigned)wrel <= 64u && (unsigned)p < SEQ) sc = s * 0.125f + bias_s[wrel];
    if (sub == 0) Ssm[q * 84 + rr] = sc;
  }
  __syncthreads();
  for (int i = t; i < 1024; i += 256){
    int r = i >> 3, seg = i & 7;
    int p = q0 + r - 32;
    float* dst = &KV[r * 68 + (seg << 3)];
    if ((unsigned)p < SEQ){
      int4 raw = *(const int4*)(vloc + base + (size_t)p * DM + (seg << 3));
      const u16* s = (const u16*)&raw;
      #pragma unroll
      for (int j = 0; j < 8; j++) dst[j] = bf2f(s[j]);
    } else {
      #pragma unroll
      for (int j = 0; j < 8; j++) dst[j] = 0.f;
    }
  }
  float mloc = -1e30f;
  for (int wrel = sub; wrel <= 64; wrel += 4) mloc = fmaxf(mloc, Ssm[q * 84 + qq + wrel]);
  mloc = fmaxf(mloc, __shfl_xor(mloc, 1));
  mloc = fmaxf(mloc, __shfl_xor(mloc, 2));
  float lloc = 0.f;
  for (int wrel = sub; wrel <= 64; wrel += 4) lloc += __expf(Ssm[q * 84 + qq + wrel] - mloc);
  lloc += __shfl_xor(lloc, 1); lloc += __shfl_xor(lloc, 2);
  float inv = 1.0f / lloc;
  for (int wrel = sub; wrel <= 64; wrel += 4)
    Ssm[q * 84 + qq + wrel] = __expf(Ssm[q * 84 + qq + wrel] - mloc) * inv;
  __syncthreads();
  float accv[16];
  #pragma unroll
  for (int i = 0; i < 16; i++) accv[i] = 0.f;
  for (int rr = 0; rr < 80; rr++){
    int r = rlo + rr;
    float pv = Ssm[q * 84 + rr];
    pv = ((unsigned)(r - q) <= 64u) ? pv : 0.f;
    const float* vr = &KV[r * 68 + (sub << 4)];
    #pragma unroll
    for (int i = 0; i < 16; i++) accv[i] += pv * vr[i];
  }
  union { u16 s[16]; int4 v[2]; } ob;
  #pragma unroll
  for (int i = 0; i < 16; i++) ob.s[i] = f2bf(accv[i]);
  u16* dst = wout + base + (size_t)(q0 + q) * DM + (sub << 4);
  *(int4*)dst = ob.v[0];
  *(int4*)(dst + 8) = ob.v[1];
}

// ---------------- gate GEMM 1: relu([lin,win,h] . wg1 + bg1) ----------------
__global__ __launch_bounds__(256) void kgate1(const u16* __restrict__ lin, const u16* __restrict__ win,
                                              const u16* __restrict__ h, const u16* __restrict__ wg1T,
                                              const float* __restrict__ bg1, u16* __restrict__ g1){
  PIPE_LDS
  int m0 = blockIdx.x << 7, n0 = blockIdx.y << 7;
  ZERO_ACC
  pipe128<3>(lin, win, h, DM, wg1T, 3072, 3072, m0, n0, LA0, LA1, LB0, LB1, acc);
  EPI_COORDS
  #pragma unroll
  for (int n = 0; n < 4; n++){
    int col = n0 + wn*64 + n*16 + (lane & 15);
    float bv = bg1[col];
    #pragma unroll
    for (int m = 0; m < 4; m++){
      int r0 = m0 + wm*64 + m*16 + ((lane >> 4) << 2);
      #pragma unroll
      for (int r = 0; r < 4; r++){
        float v = acc[m][n][r] + bv;
        g1[(size_t)(r0 + r) * DM + col] = f2bf(v > 0.f ? v : 0.f);
      }
    }
  }
}

// ---------------- gate GEMM 2 + sigmoid + convex combine ----------------
__global__ __launch_bounds__(256) void kgate2(const u16* __restrict__ g1, const u16* __restrict__ wg2T,
                                              const float* __restrict__ bg2, const u16* __restrict__ lin,
                                              const u16* __restrict__ win, u16* __restrict__ outc){
  PIPE_LDS
  int m0 = blockIdx.x << 7, n0 = blockIdx.y << 7;
  ZERO_ACC
  pipe128<1>(g1, 0, 0, DM, wg2T, DM, DM, m0, n0, LA0, LA1, LB0, LB1, acc);
  EPI_COORDS
  #pragma unroll
  for (int n = 0; n < 4; n++){
    int col = n0 + wn*64 + n*16 + (lane & 15);
    float bv = bg2[col];
    #pragma unroll
    for (int m = 0; m < 4; m++){
      int r0 = m0 + wm*64 + m*16 + ((lane >> 4) << 2);
      #pragma unroll
      for (int r = 0; r < 4; r++){
        size_t idx = (size_t)(r0 + r) * DM + col;
        float g = 1.0f / (1.0f + __expf(-(acc[m][n][r] + bv)));
        float lv = bf2f(lin[idx]), wv = bf2f(win[idx]);
        outc[idx] = f2bf(g * lv + (1.0f - g) * wv);
      }
    }
  }
}

// ---------------- final GEMM: outc . wo + bo + x -> fp32 out ----------------
__global__ __launch_bounds__(256) void kfinal(const u16* __restrict__ outc, const u16* __restrict__ woT,
                                              const float* __restrict__ bo, const float* __restrict__ x,
                                              float* __restrict__ out){
  PIPE_LDS
  int m0 = blockIdx.x << 7, n0 = blockIdx.y << 7;
  ZERO_ACC
  pipe128<1>(outc, 0, 0, DM, woT, DM, DM, m0, n0, LA0, LA1, LB0, LB1, acc);
  EPI_COORDS
  #pragma unroll
  for (int n = 0; n < 4; n++){
    int col = n0 + wn*64 + n*16 + (lane & 15);
    float bv = bo[col];
    #pragma unroll
    for (int m = 0; m < 4; m++){
      int r0 = m0 + wm*64 + m*16 + ((lane >> 4) << 2);
      #pragma unroll
      for (int r = 0; r < 4; r++){
        size_t idx = (size_t)(r0 + r) * DM + col;
        out[idx] = acc[m][n][r] + bv + x[idx];
      }
    }
  }
}

extern "C" void kernel_launch(void* const* d_in, const int* in_sizes, int n_in,
                              void* d_out, int out_size, void* d_ws, size_t ws_size,
                              hipStream_t stream)
{
  const float* x      = (const float*)d_in[0];
  const float* wq_lin = (const float*)d_in[1];  const float* bq_lin = (const float*)d_in[2];
  const float* wk_lin = (const float*)d_in[3];  const float* bk_lin = (const float*)d_in[4];
  const float* wv_lin = (const float*)d_in[5];  const float* bv_lin = (const float*)d_in[6];
  const float* wq_loc = (const float*)d_in[7];  const float* bq_loc = (const float*)d_in[8];
  const float* wk_loc = (const float*)d_in[9];  const float* bk_loc = (const float*)d_in[10];
  const float* wv_loc = (const float*)d_in[11]; const float* bv_loc = (const float*)d_in[12];
  const float* wo     = (const float*)d_in[13]; const float* bo     = (const float*)d_in[14];
  const float* wg1    = (const float*)d_in[15]; const float* bg1    = (const float*)d_in[16];
  const float* wg2    = (const float*)d_in[17]; const float* bg2    = (const float*)d_in[18];
  const float* rel_bias = (const float*)d_in[19];
  const float* ln_g   = (const float*)d_in[20]; const float* ln_b   = (const float*)d_in[21];

  char* ws = (char*)d_ws;
  size_t off = 0;
  auto alloc = [&](size_t bytes) -> void* {
    void* p = ws + off;
    off += (bytes + 255) & ~(size_t)255;
    return p;
  };
  const size_t MB2 = (size_t)1024 * 1024 * 2;
  const size_t ACT = (size_t)4096 * 1024 * 2;
  u16* wT[6]; for (int i = 0; i < 6; i++) wT[i] = (u16*)alloc(MB2);
  u16* woT   = (u16*)alloc(MB2);
  u16* wg1T  = (u16*)alloc((size_t)1024 * 3072 * 2);
  u16* wg2T  = (u16*)alloc(MB2);
  u16* hbf   = (u16*)alloc(ACT);
  u16* phiQ  = (u16*)alloc(ACT);
  u16* phiKT = (u16*)alloc(ACT);
  u16* vT    = (u16*)alloc(ACT);
  u16* qloc  = (u16*)alloc(ACT);
  u16* kloc  = (u16*)alloc(ACT);
  u16* vloc  = (u16*)alloc(ACT);
  u16* kvT   = (u16*)alloc(2 * MB2);
  float* ksum = (float*)alloc(2 * 1024 * 4);
  float* dnm  = (float*)alloc(4096 * 4);
  u16* lin   = (u16*)alloc(ACT);
  u16* win   = (u16*)alloc(ACT);
  u16* g1    = phiQ;   // reuse: phiQ dead after knum
  u16* outc  = vT;     // reuse: vT dead after kkv

  hipFuncSetAttribute((const void*)kqkv8, hipFuncAttributeMaxDynamicSharedMemorySize, 98304);

  dim3 blk(256);
  TP tp;
  tp.src[0]=wq_lin; tp.src[1]=wk_lin; tp.src[2]=wv_lin; tp.src[3]=wq_loc; tp.src[4]=wk_loc;
  tp.src[5]=wv_loc; tp.src[6]=wo; tp.src[7]=wg1; tp.src[8]=wg2;
  tp.dst[0]=wT[0]; tp.dst[1]=wT[1]; tp.dst[2]=wT[2]; tp.dst[3]=wT[3]; tp.dst[4]=wT[4];
  tp.dst[5]=wT[5]; tp.dst[6]=woT; tp.dst[7]=wg1T; tp.dst[8]=wg2T;
  for (int i = 0; i < 9; i++) tp.K[i] = (i == 7) ? 3072 : 1024;
  ktransall<<<dim3(16,48,9), blk, 0, stream>>>(tp);

  kln<<<4096, blk, 0, stream>>>(x, ln_g, ln_b, hbf);

  kqkv8<<<768, 512, 98304, stream>>>(hbf, wT[0], wT[1], wT[2], wT[3], wT[4], wT[5],
                                     bq_lin, bk_lin, bv_lin, bq_loc, bk_loc, bv_loc,
                                     phiQ, phiKT, vT, qloc, kloc, vloc);

  ksumk<<<2048, blk, 0, stream>>>(phiKT, ksum);
  kdenom<<<4096, blk, 0, stream>>>(phiQ, ksum, dnm);
  kkv<<<dim3(8,8,2), blk, 0, stream>>>(vT, phiKT, kvT);
  knum<<<dim3(16,8,2), blk, 0, stream>>>(phiQ, kvT, dnm, lin);

  kwin<<<dim3(32,16,2), blk, 0, stream>>>(qloc, kloc, vloc, rel_bias, win);

  kgate1<<<dim3(32,8), blk, 0, stream>>>(lin, win, hbf, wg1T, bg1, g1);
  kgate2<<<dim3(32,8), blk, 0, stream>>>(g1, wg2T, bg2, lin, win, outc);
  kfinal<<<dim3(32,8), blk, 0, stream>>>(outc, woT, bo, x, (float*)d_out);
}